// Round 4
// baseline (318.188 us; speedup 1.0000x reference)
//
#include <hip/hip_runtime.h>

#define F16 _Float16
typedef _Float16 f16x8 __attribute__((ext_vector_type(8)));
typedef _Float16 f16x4 __attribute__((ext_vector_type(4)));
typedef float f32x4 __attribute__((ext_vector_type(4)));

#define NB    4
#define CIN   512
#define NN    4096
#define KCH   256
#define OCH   512
#define BNEPS 1e-5f
#define PSET  ((size_t)NB * NN * KCH)        // elements per partial set
#define NBNN  (NB * NN)

// ---------------------------------------------------------------- transpose
__global__ __launch_bounds__(256) void k_transpose(const float* __restrict__ x,
                                                   F16* __restrict__ xT) {
    __shared__ float tile[64][65];
    int b = blockIdx.z, n0 = blockIdx.y * 64, c0 = blockIdx.x * 64;
    int t = threadIdx.x;
    const float* xb = x + (size_t)b * CIN * NN;
#pragma unroll
    for (int i = 0; i < 4; i++) {
        int c = (t >> 4) + i * 16;
        int n = (t & 15) * 4;
        float4 v = *(const float4*)&xb[(size_t)(c0 + c) * NN + n0 + n];
        tile[c][n + 0] = v.x; tile[c][n + 1] = v.y;
        tile[c][n + 2] = v.z; tile[c][n + 3] = v.w;
    }
    __syncthreads();
    F16* xTb = xT + (size_t)b * NN * CIN;
#pragma unroll
    for (int i = 0; i < 4; i++) {
        int n = (t >> 4) + i * 16;
        int c = (t & 15) * 4;
        f16x4 o;
        o[0] = (F16)tile[c + 0][n]; o[1] = (F16)tile[c + 1][n];
        o[2] = (F16)tile[c + 2][n]; o[3] = (F16)tile[c + 3][n];
        *(f16x4*)&xTb[(size_t)(n0 + n) * CIN + c0 + c] = o;
    }
}

// ---------------------------------------------------------------- K/V GEMM
__global__ __launch_bounds__(256) void k_kv_gemm(
    const F16* __restrict__ xT,
    const float* __restrict__ key_w, const float* __restrict__ key_b,
    const float* __restrict__ gamma, const float* __restrict__ beta,
    const float* __restrict__ mean,  const float* __restrict__ var,
    const float* __restrict__ value_w, const float* __restrict__ value_b,
    F16* __restrict__ KQt, F16* __restrict__ Vg) {
    __shared__ F16 Al[128][40];
    __shared__ F16 Bl[128][40];
    int b = blockIdx.z;
    int m0 = blockIdx.y * 128;
    int n0 = blockIdx.x * 128;
    int t = threadIdx.x, w = t >> 6, l = t & 63;
    int wr = w >> 1, wc = w & 1;
    int lr = l >> 4, lc = l & 15;
    f32x4 acc[4][4];
    const f32x4 fz = {0.f, 0.f, 0.f, 0.f};
#pragma unroll
    for (int i = 0; i < 4; i++)
#pragma unroll
        for (int j = 0; j < 4; j++) acc[i][j] = fz;
    const F16* xb = xT + (size_t)b * NN * CIN;

    for (int kt = 0; kt < CIN / 32; kt++) {
        int c0 = kt * 32;
        __syncthreads();
#pragma unroll
        for (int p = 0; p < 4; p++) {
            int row = (t >> 3) + p * 32;
            int cc = (t & 7) * 4;
            int rg = m0 + row;
            const float* src = (rg < 256) ? (key_w + (size_t)rg * CIN)
                                          : (value_w + (size_t)(rg - 256) * CIN);
            float4 v = *(const float4*)&src[c0 + cc];
            f16x4 h; h[0] = (F16)v.x; h[1] = (F16)v.y; h[2] = (F16)v.z; h[3] = (F16)v.w;
            *(f16x4*)&Al[row][cc] = h;
        }
#pragma unroll
        for (int p = 0; p < 2; p++) {
            int row = (t >> 2) + p * 64;
            int cc = (t & 3) * 8;
            *(int4*)&Bl[row][cc] = *(const int4*)&xb[(size_t)(n0 + row) * CIN + c0 + cc];
        }
        __syncthreads();
        f16x8 a[4];
#pragma unroll
        for (int fi = 0; fi < 4; fi++)
            a[fi] = *(f16x8*)&Al[wr * 64 + fi * 16 + lc][lr * 8];
#pragma unroll
        for (int fj = 0; fj < 4; fj++) {
            f16x8 bb = *(f16x8*)&Bl[wc * 64 + fj * 16 + lc][lr * 8];
#pragma unroll
            for (int fi = 0; fi < 4; fi++)
                acc[fi][fj] = __builtin_amdgcn_mfma_f32_16x16x32_f16(a[fi], bb, acc[fi][fj], 0, 0, 0);
        }
    }

    if (m0 < 256) {
#pragma unroll
        for (int fi = 0; fi < 4; fi++) {
            int ch0 = m0 + wr * 64 + fi * 16 + lr * 4;
            float invs[4], mns[4], bts[4], kbs[4];
#pragma unroll
            for (int r = 0; r < 4; r++) {
                int ch = ch0 + r;
                invs[r] = gamma[ch] * rsqrtf(var[ch] + BNEPS);
                mns[r] = mean[ch]; bts[r] = beta[ch]; kbs[r] = key_b[ch];
            }
#pragma unroll
            for (int fj = 0; fj < 4; fj++) {
                int n = n0 + wc * 64 + fj * 16 + lc;
                f16x4 o;
#pragma unroll
                for (int r = 0; r < 4; r++) {
                    float v = (acc[fi][fj][r] + kbs[r] - mns[r]) * invs[r] + bts[r];
                    v = fmaxf(v, 0.0f);
                    o[r] = (F16)v;
                }
                *(f16x4*)&KQt[((size_t)b * NN + n) * KCH + ch0] = o;
            }
        }
    } else {
#pragma unroll
        for (int fi = 0; fi < 4; fi++) {
            int v0 = m0 - 256 + wr * 64 + fi * 16 + lr * 4;
#pragma unroll
            for (int fj = 0; fj < 4; fj++) {
                int n = n0 + wc * 64 + fj * 16 + lc;
#pragma unroll
                for (int r = 0; r < 4; r++) {
                    float vv = acc[fi][fj][r] + value_b[v0 + r];
                    Vg[((size_t)b * KCH + v0 + r) * NN + n] = (F16)vv;
                }
            }
        }
    }
}

// ---------------------------------------------------------------- flash attention
// 32 q-rows/wave (2 fragments), q-tile 128/block, split-K (ksets = 1<<log2ks).
// LDS 76.8 KB -> 2 blocks/CU at ksets=4 (512 blocks). Half-k-column online
// softmax: S computed 32 k-cols at a time; P LDS buffer is half-width [32][34].
__global__ __launch_bounds__(256, 2) void k_flash(const F16* __restrict__ KQt,
                                                  const F16* __restrict__ Vg,
                                                  F16* __restrict__ parts,
                                                  float* __restrict__ Lbuf,
                                                  int log2ks) {
    __shared__ F16 Kl[64 * 260];
    __shared__ F16 Vl[256 * 68];
    __shared__ F16 Pl[4][32 * 34];
    int bid = blockIdx.x;
    int xcd = bid & 7;
    int b = xcd >> 1;                          // batch pinned to an XCD pair
    int hi = bid >> 3;
    int nset = 1 << log2ks;
    int kset = hi & (nset - 1);
    int qtile = (xcd & 1) * 16 + (hi >> log2ks);   // 0..31 per batch
    int n0 = qtile * 128;
    int kper = NN >> log2ks;
    int kbase = kset * kper;
    int ntile = kper >> 6;
    int t = threadIdx.x, w = t >> 6, l = t & 63;
    int lr = l >> 4, lc = l & 15;
    const F16* kqb = KQt + (size_t)b * NN * KCH;
    const F16* vgb = Vg + (size_t)b * KCH * NN;
    const float scale = 0.0625f;

    // Q rows -> registers: wave owns rows n0 + w*32 + g*16 + lc
    f16x8 qreg[2][8];
#pragma unroll
    for (int g = 0; g < 2; g++) {
        const F16* qrow = kqb + (size_t)(n0 + w * 32 + g * 16 + lc) * KCH + lr * 8;
#pragma unroll
        for (int ks = 0; ks < 8; ks++)
            qreg[g][ks] = *(const f16x8*)&qrow[ks * 32];
    }

    f32x4 acc[2][16];
    const f32x4 fz = {0.f, 0.f, 0.f, 0.f};
#pragma unroll
    for (int g = 0; g < 2; g++)
#pragma unroll
        for (int i = 0; i < 16; i++) acc[g][i] = fz;
    float m_run[2][4] = {{-1e30f, -1e30f, -1e30f, -1e30f},
                         {-1e30f, -1e30f, -1e30f, -1e30f}};
    float l_run[2][4] = {{0.f, 0.f, 0.f, 0.f}, {0.f, 0.f, 0.f, 0.f}};

    int krow = t >> 5, kcol = (t & 31) * 8;    // K staging: 8 rows/pass
    int vrow = t >> 3, vcol = (t & 7) * 8;     // V staging: 32 rows/pass

    for (int mt = 0; mt < ntile; mt++) {
        int m0 = kbase + mt * 64;
        __syncthreads();
#pragma unroll
        for (int p = 0; p < 8; p++) {
            int4 tmp = *(const int4*)&kqb[(size_t)(m0 + krow + p * 8) * KCH + kcol];
            *(int4*)&Kl[(krow + p * 8) * 260 + kcol] = tmp;
        }
#pragma unroll
        for (int p = 0; p < 8; p++) {
            int4 tmp = *(const int4*)&vgb[(size_t)(vrow + p * 32) * NN + m0 + vcol];
            *(int4*)&Vl[(vrow + p * 32) * 68 + vcol] = tmp;
        }
        __syncthreads();

        // two 32-key halves: QK^T -> online softmax -> PV
#pragma unroll
        for (int h = 0; h < 2; h++) {
            f32x4 s[2][2];
            s[0][0] = fz; s[0][1] = fz; s[1][0] = fz; s[1][1] = fz;
#pragma unroll
            for (int ks = 0; ks < 8; ks++) {
#pragma unroll
                for (int f = 0; f < 2; f++) {
                    f16x8 bb = *(f16x8*)&Kl[((h * 2 + f) * 16 + lc) * 260 + ks * 32 + lr * 8];
                    s[0][f] = __builtin_amdgcn_mfma_f32_16x16x32_f16(qreg[0][ks], bb, s[0][f], 0, 0, 0);
                    s[1][f] = __builtin_amdgcn_mfma_f32_16x16x32_f16(qreg[1][ks], bb, s[1][f], 0, 0, 0);
                }
            }
            // online softmax over this 32-key half (deferred rescale, THR=8)
#pragma unroll
            for (int g = 0; g < 2; g++) {
#pragma unroll
                for (int r = 0; r < 4; r++) {
                    float mx = fmaxf(s[g][0][r], s[g][1][r]);
#pragma unroll
                    for (int off = 1; off < 16; off <<= 1)
                        mx = fmaxf(mx, __shfl_xor(mx, off, 64));
                    mx *= scale;
                    if (mx > m_run[g][r] + 8.0f) {
                        float corr = __expf(m_run[g][r] - mx);
                        m_run[g][r] = mx;
                        l_run[g][r] *= corr;
#pragma unroll
                        for (int fv = 0; fv < 16; fv++) acc[g][fv][r] *= corr;
                    }
                    float p0 = __expf(s[g][0][r] * scale - m_run[g][r]);
                    float p1 = __expf(s[g][1][r] * scale - m_run[g][r]);
                    int prow = g * 16 + lr * 4 + r;
                    Pl[w][prow * 34 + lc] = (F16)p0;
                    Pl[w][prow * 34 + 16 + lc] = (F16)p1;
                    float ps = p0 + p1;
#pragma unroll
                    for (int off = 1; off < 16; off <<= 1)
                        ps += __shfl_xor(ps, off, 64);
                    l_run[g][r] += ps;
                }
            }
            // PV for this half (Pl per-wave; in-wave DS ordering, no barrier)
#pragma unroll
            for (int g = 0; g < 2; g++) {
                f16x8 a = *(f16x8*)&Pl[w][(g * 16 + lc) * 34 + lr * 8];
#pragma unroll
                for (int fv = 0; fv < 16; fv++) {
                    f16x8 bb = *(f16x8*)&Vl[(fv * 16 + lc) * 68 + h * 32 + lr * 8];
                    acc[g][fv] = __builtin_amdgcn_mfma_f32_16x16x32_f16(a, bb, acc[g][fv], 0, 0, 0);
                }
            }
        }
    }

    // epilogue: normalized partial + L = m + ln(l)
    F16* cb = parts + (size_t)kset * PSET + (size_t)b * NN * KCH;
    float* Lb = Lbuf + ((size_t)kset * NB + b) * NN;
#pragma unroll
    for (int g = 0; g < 2; g++) {
#pragma unroll
        for (int r = 0; r < 4; r++) {
            int n = n0 + w * 32 + g * 16 + lr * 4 + r;
            float inv = 1.0f / l_run[g][r];
#pragma unroll
            for (int fv = 0; fv < 16; fv++)
                cb[(size_t)n * KCH + fv * 16 + lc] = (F16)(acc[g][fv][r] * inv);
            if (lc == 0) Lb[n] = m_run[g][r] + __logf(l_run[g][r]);
        }
    }
}

// ---------------------------------------------------------------- combine (split-K merge)
__global__ __launch_bounds__(256) void k_combine(const F16* __restrict__ parts,
                                                 const float* __restrict__ Lbuf,
                                                 F16* __restrict__ ctxT,
                                                 int nset) {
    int idx = blockIdx.x * 256 + threadIdx.x;       // over B*N*32
    int n = idx >> 5;
    int v8 = (idx & 31) * 8;
    bool k4 = (nset == 4);
    float L0 = Lbuf[n];
    float L1 = Lbuf[NBNN + n];
    float L2 = k4 ? Lbuf[2 * NBNN + n] : -1e30f;
    float L3 = k4 ? Lbuf[3 * NBNN + n] : -1e30f;
    float M = fmaxf(fmaxf(L0, L1), fmaxf(L2, L3));
    float w0 = __expf(L0 - M), w1 = __expf(L1 - M);
    float w2 = k4 ? __expf(L2 - M) : 0.f;
    float w3 = k4 ? __expf(L3 - M) : 0.f;
    float inv = 1.0f / (w0 + w1 + w2 + w3);
    w0 *= inv; w1 *= inv; w2 *= inv; w3 *= inv;
    f16x8 p0 = *(const f16x8*)&parts[(size_t)n * KCH + v8];
    f16x8 p1 = *(const f16x8*)&parts[PSET + (size_t)n * KCH + v8];
    f16x8 o;
    if (k4) {
        f16x8 p2 = *(const f16x8*)&parts[2 * PSET + (size_t)n * KCH + v8];
        f16x8 p3 = *(const f16x8*)&parts[3 * PSET + (size_t)n * KCH + v8];
#pragma unroll
        for (int j = 0; j < 8; j++)
            o[j] = (F16)(w0 * (float)p0[j] + w1 * (float)p1[j] +
                         w2 * (float)p2[j] + w3 * (float)p3[j]);
    } else {
#pragma unroll
        for (int j = 0; j < 8; j++)
            o[j] = (F16)(w0 * (float)p0[j] + w1 * (float)p1[j]);
    }
    *(f16x8*)&ctxT[(size_t)n * KCH + v8] = o;
}

// ---------------------------------------------------------------- out GEMM
__global__ __launch_bounds__(256) void k_out_gemm(const F16* __restrict__ ctxT,
                                                  const float* __restrict__ w_w,
                                                  const float* __restrict__ w_b,
                                                  float* __restrict__ out) {
    __shared__ F16 Al[128][40];
    __shared__ F16 Bl[128][40];
    int b = blockIdx.z;
    int m0 = blockIdx.y * 128;
    int n0 = blockIdx.x * 128;
    int t = threadIdx.x, w = t >> 6, l = t & 63;
    int wr = w >> 1, wc = w & 1;
    int lr = l >> 4, lc = l & 15;
    f32x4 acc[4][4];
    const f32x4 fz = {0.f, 0.f, 0.f, 0.f};
#pragma unroll
    for (int i = 0; i < 4; i++)
#pragma unroll
        for (int j = 0; j < 4; j++) acc[i][j] = fz;
    const F16* cb = ctxT + (size_t)b * NN * KCH;

    for (int kt = 0; kt < KCH / 32; kt++) {
        int c0 = kt * 32;
        __syncthreads();
#pragma unroll
        for (int p = 0; p < 4; p++) {
            int row = (t >> 3) + p * 32;
            int cc = (t & 7) * 4;
            float4 v = *(const float4*)&w_w[(size_t)(m0 + row) * KCH + c0 + cc];
            f16x4 h; h[0] = (F16)v.x; h[1] = (F16)v.y; h[2] = (F16)v.z; h[3] = (F16)v.w;
            *(f16x4*)&Al[row][cc] = h;
        }
#pragma unroll
        for (int p = 0; p < 2; p++) {
            int row = (t >> 2) + p * 64;
            int cc = (t & 3) * 8;
            *(int4*)&Bl[row][cc] = *(const int4*)&cb[(size_t)(n0 + row) * KCH + c0 + cc];
        }
        __syncthreads();
        f16x8 a[4];
#pragma unroll
        for (int fi = 0; fi < 4; fi++)
            a[fi] = *(f16x8*)&Al[wr * 64 + fi * 16 + lc][lr * 8];
#pragma unroll
        for (int fj = 0; fj < 4; fj++) {
            f16x8 bb = *(f16x8*)&Bl[wc * 64 + fj * 16 + lc][lr * 8];
#pragma unroll
            for (int fi = 0; fi < 4; fi++)
                acc[fi][fj] = __builtin_amdgcn_mfma_f32_16x16x32_f16(a[fi], bb, acc[fi][fj], 0, 0, 0);
        }
    }

#pragma unroll
    for (int fi = 0; fi < 4; fi++) {
        int o0 = m0 + wr * 64 + fi * 16 + lr * 4;
#pragma unroll
        for (int fj = 0; fj < 4; fj++) {
            int n = n0 + wc * 64 + fj * 16 + lc;
#pragma unroll
            for (int r = 0; r < 4; r++) {
                out[((size_t)b * OCH + o0 + r) * NN + n] = acc[fi][fj][r] + w_b[o0 + r];
            }
        }
    }
}

// ---------------------------------------------------------------- launch
extern "C" void kernel_launch(void* const* d_in, const int* in_sizes, int n_in,
                              void* d_out, int out_size, void* d_ws, size_t ws_size,
                              hipStream_t stream) {
    const float* x       = (const float*)d_in[0];
    const float* key_w   = (const float*)d_in[1];
    const float* key_b   = (const float*)d_in[2];
    const float* gamma   = (const float*)d_in[3];
    const float* beta    = (const float*)d_in[4];
    const float* mean    = (const float*)d_in[5];
    const float* var     = (const float*)d_in[6];
    const float* value_w = (const float*)d_in[7];
    const float* value_b = (const float*)d_in[8];
    const float* w_w     = (const float*)d_in[9];
    const float* w_b     = (const float*)d_in[10];
    float* out = (float*)d_out;
    char* ws = (char*)d_ws;

    // workspace budget: ksets=4 needs parts 33.55M + KQt 8.39M + Vg 8.39M + L 0.26M
    const size_t need4 = 4 * (PSET * 2) + 2 * 8388608ull + 4 * NBNN * 4ull;
    int log2ks = (ws_size >= need4) ? 2 : 1;
    int nset = 1 << log2ks;
    size_t parts_off = 0;
    size_t kqt_off   = (size_t)nset * PSET * 2;     // parts end
    size_t vg_off    = kqt_off + 8388608ull;
    size_t l_off     = vg_off + 8388608ull;

    F16*   xT    = (F16*)(ws);                 // dead after kv_gemm; parts overlay
    F16*   parts = (F16*)(ws + parts_off);
    F16*   KQt   = (F16*)(ws + kqt_off);
    F16*   ctxT  = (F16*)(ws + kqt_off);       // overlays KQt (dead after flash)
    F16*   Vg    = (F16*)(ws + vg_off);
    float* Lbuf  = (float*)(ws + l_off);

    hipLaunchKernelGGL(k_transpose, dim3(8, 64, 4), dim3(256), 0, stream, x, xT);
    hipLaunchKernelGGL(k_kv_gemm, dim3(32, 4, 4), dim3(256), 0, stream,
                       xT, key_w, key_b, gamma, beta, mean, var, value_w, value_b, KQt, Vg);
    hipLaunchKernelGGL(k_flash, dim3(128 * nset), dim3(256), 0, stream,
                       KQt, Vg, parts, Lbuf, log2ks);
    hipLaunchKernelGGL(k_combine, dim3(2048), dim3(256), 0, stream, parts, Lbuf, ctxT, nset);
    hipLaunchKernelGGL(k_out_gemm, dim3(32, 4, 4), dim3(256), 0, stream, ctxT, w_w, w_b, out);
}

// Round 5
// 293.298 us; speedup vs baseline: 1.0849x; 1.0849x over previous
//
#include <hip/hip_runtime.h>

#define F16 _Float16
typedef _Float16 f16x8 __attribute__((ext_vector_type(8)));
typedef _Float16 f16x4 __attribute__((ext_vector_type(4)));
typedef float f32x4 __attribute__((ext_vector_type(4)));

#define NB    4
#define CIN   512
#define NN    4096
#define KCH   256
#define OCH   512
#define BNEPS 1e-5f
#define PSET  ((size_t)NB * NN * KCH)        // elements per partial set
#define NBNN  (NB * NN)

// ---------------------------------------------------------------- transpose
__global__ __launch_bounds__(256) void k_transpose(const float* __restrict__ x,
                                                   F16* __restrict__ xT) {
    __shared__ float tile[64][65];
    int b = blockIdx.z, n0 = blockIdx.y * 64, c0 = blockIdx.x * 64;
    int t = threadIdx.x;
    const float* xb = x + (size_t)b * CIN * NN;
#pragma unroll
    for (int i = 0; i < 4; i++) {
        int c = (t >> 4) + i * 16;
        int n = (t & 15) * 4;
        float4 v = *(const float4*)&xb[(size_t)(c0 + c) * NN + n0 + n];
        tile[c][n + 0] = v.x; tile[c][n + 1] = v.y;
        tile[c][n + 2] = v.z; tile[c][n + 3] = v.w;
    }
    __syncthreads();
    F16* xTb = xT + (size_t)b * NN * CIN;
#pragma unroll
    for (int i = 0; i < 4; i++) {
        int n = (t >> 4) + i * 16;
        int c = (t & 15) * 4;
        f16x4 o;
        o[0] = (F16)tile[c + 0][n]; o[1] = (F16)tile[c + 1][n];
        o[2] = (F16)tile[c + 2][n]; o[3] = (F16)tile[c + 3][n];
        *(f16x4*)&xTb[(size_t)(n0 + n) * CIN + c0 + c] = o;
    }
}

// ---------------------------------------------------------------- K/V GEMM
__global__ __launch_bounds__(256) void k_kv_gemm(
    const F16* __restrict__ xT,
    const float* __restrict__ key_w, const float* __restrict__ key_b,
    const float* __restrict__ gamma, const float* __restrict__ beta,
    const float* __restrict__ mean,  const float* __restrict__ var,
    const float* __restrict__ value_w, const float* __restrict__ value_b,
    F16* __restrict__ KQt, F16* __restrict__ Vg) {
    __shared__ F16 Al[128][40];
    __shared__ F16 Bl[128][40];
    int b = blockIdx.z;
    int m0 = blockIdx.y * 128;
    int n0 = blockIdx.x * 128;
    int t = threadIdx.x, w = t >> 6, l = t & 63;
    int wr = w >> 1, wc = w & 1;
    int lr = l >> 4, lc = l & 15;
    f32x4 acc[4][4];
    const f32x4 fz = {0.f, 0.f, 0.f, 0.f};
#pragma unroll
    for (int i = 0; i < 4; i++)
#pragma unroll
        for (int j = 0; j < 4; j++) acc[i][j] = fz;
    const F16* xb = xT + (size_t)b * NN * CIN;

    for (int kt = 0; kt < CIN / 32; kt++) {
        int c0 = kt * 32;
        __syncthreads();
#pragma unroll
        for (int p = 0; p < 4; p++) {
            int row = (t >> 3) + p * 32;
            int cc = (t & 7) * 4;
            int rg = m0 + row;
            const float* src = (rg < 256) ? (key_w + (size_t)rg * CIN)
                                          : (value_w + (size_t)(rg - 256) * CIN);
            float4 v = *(const float4*)&src[c0 + cc];
            f16x4 h; h[0] = (F16)v.x; h[1] = (F16)v.y; h[2] = (F16)v.z; h[3] = (F16)v.w;
            *(f16x4*)&Al[row][cc] = h;
        }
#pragma unroll
        for (int p = 0; p < 2; p++) {
            int row = (t >> 2) + p * 64;
            int cc = (t & 3) * 8;
            *(int4*)&Bl[row][cc] = *(const int4*)&xb[(size_t)(n0 + row) * CIN + c0 + cc];
        }
        __syncthreads();
        f16x8 a[4];
#pragma unroll
        for (int fi = 0; fi < 4; fi++)
            a[fi] = *(f16x8*)&Al[wr * 64 + fi * 16 + lc][lr * 8];
#pragma unroll
        for (int fj = 0; fj < 4; fj++) {
            f16x8 bb = *(f16x8*)&Bl[wc * 64 + fj * 16 + lc][lr * 8];
#pragma unroll
            for (int fi = 0; fi < 4; fi++)
                acc[fi][fj] = __builtin_amdgcn_mfma_f32_16x16x32_f16(a[fi], bb, acc[fi][fj], 0, 0, 0);
        }
    }

    if (m0 < 256) {
#pragma unroll
        for (int fi = 0; fi < 4; fi++) {
            int ch0 = m0 + wr * 64 + fi * 16 + lr * 4;
            float invs[4], mns[4], bts[4], kbs[4];
#pragma unroll
            for (int r = 0; r < 4; r++) {
                int ch = ch0 + r;
                invs[r] = gamma[ch] * rsqrtf(var[ch] + BNEPS);
                mns[r] = mean[ch]; bts[r] = beta[ch]; kbs[r] = key_b[ch];
            }
#pragma unroll
            for (int fj = 0; fj < 4; fj++) {
                int n = n0 + wc * 64 + fj * 16 + lc;
                f16x4 o;
#pragma unroll
                for (int r = 0; r < 4; r++) {
                    float v = (acc[fi][fj][r] + kbs[r] - mns[r]) * invs[r] + bts[r];
                    v = fmaxf(v, 0.0f);
                    o[r] = (F16)v;
                }
                *(f16x4*)&KQt[((size_t)b * NN + n) * KCH + ch0] = o;
            }
        }
    } else {
#pragma unroll
        for (int fi = 0; fi < 4; fi++) {
            int v0 = m0 - 256 + wr * 64 + fi * 16 + lr * 4;
#pragma unroll
            for (int fj = 0; fj < 4; fj++) {
                int n = n0 + wc * 64 + fj * 16 + lc;
#pragma unroll
                for (int r = 0; r < 4; r++) {
                    float vv = acc[fi][fj][r] + value_b[v0 + r];
                    Vg[((size_t)b * KCH + v0 + r) * NN + n] = (F16)vv;
                }
            }
        }
    }
}

// ---------------------------------------------------------------- flash attention
// 32 q-rows/wave, q-tile 128/block, split-K with 4 sets. 512 blocks = 2/CU
// (LDS 76.8 KB). XCD mapping: each XCD serves ONE batch and TWO key-streams
// (kset = (xcd&1)*2 + (hi&1)) — the round-3-proven L2 regime.
__global__ __launch_bounds__(256, 2) void k_flash(const F16* __restrict__ KQt,
                                                  const F16* __restrict__ Vg,
                                                  F16* __restrict__ parts,
                                                  float* __restrict__ Lbuf) {
    __shared__ F16 Kl[64 * 260];
    __shared__ F16 Vl[256 * 68];
    __shared__ F16 Pl[4][32 * 34];
    int bid = blockIdx.x;
    int xcd = bid & 7;
    int b = xcd >> 1;                          // batch pinned to an XCD pair
    int hi = bid >> 3;                         // 0..63
    int kset = (xcd & 1) * 2 + (hi & 1);       // 2 streams per XCD
    int qtile = hi >> 1;                       // 0..31
    int n0 = qtile * 128;
    int kbase = kset * 1024;
    int t = threadIdx.x, w = t >> 6, l = t & 63;
    int lr = l >> 4, lc = l & 15;
    const F16* kqb = KQt + (size_t)b * NN * KCH;
    const F16* vgb = Vg + (size_t)b * KCH * NN;
    const float scale = 0.0625f;

    // Q rows -> registers: wave owns rows n0 + w*32 + g*16 + lc
    f16x8 qreg[2][8];
#pragma unroll
    for (int g = 0; g < 2; g++) {
        const F16* qrow = kqb + (size_t)(n0 + w * 32 + g * 16 + lc) * KCH + lr * 8;
#pragma unroll
        for (int ks = 0; ks < 8; ks++)
            qreg[g][ks] = *(const f16x8*)&qrow[ks * 32];
    }

    f32x4 acc[2][16];
    const f32x4 fz = {0.f, 0.f, 0.f, 0.f};
#pragma unroll
    for (int g = 0; g < 2; g++)
#pragma unroll
        for (int i = 0; i < 16; i++) acc[g][i] = fz;
    float m_run[2][4] = {{-1e30f, -1e30f, -1e30f, -1e30f},
                         {-1e30f, -1e30f, -1e30f, -1e30f}};
    float l_run[2][4] = {{0.f, 0.f, 0.f, 0.f}, {0.f, 0.f, 0.f, 0.f}};

    int krow = t >> 5, kcol = (t & 31) * 8;    // K staging: 8 rows/pass
    int vrow = t >> 3, vcol = (t & 7) * 8;     // V staging: 32 rows/pass

    for (int mt = 0; mt < 16; mt++) {
        int m0 = kbase + mt * 64;
        __syncthreads();
#pragma unroll
        for (int p = 0; p < 8; p++) {
            int4 tmp = *(const int4*)&kqb[(size_t)(m0 + krow + p * 8) * KCH + kcol];
            *(int4*)&Kl[(krow + p * 8) * 260 + kcol] = tmp;
        }
#pragma unroll
        for (int p = 0; p < 8; p++) {
            int4 tmp = *(const int4*)&vgb[(size_t)(vrow + p * 32) * NN + m0 + vcol];
            *(int4*)&Vl[(vrow + p * 32) * 68 + vcol] = tmp;
        }
        __syncthreads();

        // two 32-key halves: QK^T -> online softmax -> PV
#pragma unroll
        for (int h = 0; h < 2; h++) {
            f32x4 s[2][2];
            s[0][0] = fz; s[0][1] = fz; s[1][0] = fz; s[1][1] = fz;
#pragma unroll
            for (int ks = 0; ks < 8; ks++) {
#pragma unroll
                for (int f = 0; f < 2; f++) {
                    f16x8 bb = *(f16x8*)&Kl[((h * 2 + f) * 16 + lc) * 260 + ks * 32 + lr * 8];
                    s[0][f] = __builtin_amdgcn_mfma_f32_16x16x32_f16(qreg[0][ks], bb, s[0][f], 0, 0, 0);
                    s[1][f] = __builtin_amdgcn_mfma_f32_16x16x32_f16(qreg[1][ks], bb, s[1][f], 0, 0, 0);
                }
            }
            // online softmax over this 32-key half (deferred rescale, THR=8)
#pragma unroll
            for (int g = 0; g < 2; g++) {
#pragma unroll
                for (int r = 0; r < 4; r++) {
                    float mx = fmaxf(s[g][0][r], s[g][1][r]);
#pragma unroll
                    for (int off = 1; off < 16; off <<= 1)
                        mx = fmaxf(mx, __shfl_xor(mx, off, 64));
                    mx *= scale;
                    if (mx > m_run[g][r] + 8.0f) {
                        float corr = __expf(m_run[g][r] - mx);
                        m_run[g][r] = mx;
                        l_run[g][r] *= corr;
#pragma unroll
                        for (int fv = 0; fv < 16; fv++) acc[g][fv][r] *= corr;
                    }
                    float p0 = __expf(s[g][0][r] * scale - m_run[g][r]);
                    float p1 = __expf(s[g][1][r] * scale - m_run[g][r]);
                    int prow = g * 16 + lr * 4 + r;
                    Pl[w][prow * 34 + lc] = (F16)p0;
                    Pl[w][prow * 34 + 16 + lc] = (F16)p1;
                    float ps = p0 + p1;
#pragma unroll
                    for (int off = 1; off < 16; off <<= 1)
                        ps += __shfl_xor(ps, off, 64);
                    l_run[g][r] += ps;
                }
            }
            // PV for this half: V fragment read ONCE, fed to both g-fragments
            f16x8 a0 = *(f16x8*)&Pl[w][(0 * 16 + lc) * 34 + lr * 8];
            f16x8 a1 = *(f16x8*)&Pl[w][(1 * 16 + lc) * 34 + lr * 8];
#pragma unroll
            for (int fv = 0; fv < 16; fv++) {
                f16x8 bb = *(f16x8*)&Vl[(fv * 16 + lc) * 68 + h * 32 + lr * 8];
                acc[0][fv] = __builtin_amdgcn_mfma_f32_16x16x32_f16(a0, bb, acc[0][fv], 0, 0, 0);
                acc[1][fv] = __builtin_amdgcn_mfma_f32_16x16x32_f16(a1, bb, acc[1][fv], 0, 0, 0);
            }
        }
    }

    // epilogue: normalized partial + L = m + ln(l)
    F16* cb = parts + (size_t)kset * PSET + (size_t)b * NN * KCH;
    float* Lb = Lbuf + ((size_t)kset * NB + b) * NN;
#pragma unroll
    for (int g = 0; g < 2; g++) {
#pragma unroll
        for (int r = 0; r < 4; r++) {
            int n = n0 + w * 32 + g * 16 + lr * 4 + r;
            float inv = 1.0f / l_run[g][r];
#pragma unroll
            for (int fv = 0; fv < 16; fv++)
                cb[(size_t)n * KCH + fv * 16 + lc] = (F16)(acc[g][fv][r] * inv);
            if (lc == 0) Lb[n] = m_run[g][r] + __logf(l_run[g][r]);
        }
    }
}

// ---------------------------------------------------------------- combine (4-way split-K merge)
__global__ __launch_bounds__(256) void k_combine(const F16* __restrict__ parts,
                                                 const float* __restrict__ Lbuf,
                                                 F16* __restrict__ ctxT) {
    int idx = blockIdx.x * 256 + threadIdx.x;       // over B*N*32
    int n = idx >> 5;
    int v8 = (idx & 31) * 8;
    float L0 = Lbuf[n];
    float L1 = Lbuf[NBNN + n];
    float L2 = Lbuf[2 * NBNN + n];
    float L3 = Lbuf[3 * NBNN + n];
    float M = fmaxf(fmaxf(L0, L1), fmaxf(L2, L3));
    float w0 = __expf(L0 - M), w1 = __expf(L1 - M);
    float w2 = __expf(L2 - M), w3 = __expf(L3 - M);
    float inv = 1.0f / (w0 + w1 + w2 + w3);
    w0 *= inv; w1 *= inv; w2 *= inv; w3 *= inv;
    f16x8 p0 = *(const f16x8*)&parts[(size_t)n * KCH + v8];
    f16x8 p1 = *(const f16x8*)&parts[PSET + (size_t)n * KCH + v8];
    f16x8 p2 = *(const f16x8*)&parts[2 * PSET + (size_t)n * KCH + v8];
    f16x8 p3 = *(const f16x8*)&parts[3 * PSET + (size_t)n * KCH + v8];
    f16x8 o;
#pragma unroll
    for (int j = 0; j < 8; j++)
        o[j] = (F16)(w0 * (float)p0[j] + w1 * (float)p1[j] +
                     w2 * (float)p2[j] + w3 * (float)p3[j]);
    *(f16x8*)&ctxT[(size_t)n * KCH + v8] = o;
}

// ---------------------------------------------------------------- out GEMM
__global__ __launch_bounds__(256) void k_out_gemm(const F16* __restrict__ ctxT,
                                                  const float* __restrict__ w_w,
                                                  const float* __restrict__ w_b,
                                                  float* __restrict__ out) {
    __shared__ F16 Al[128][40];
    __shared__ F16 Bl[128][40];
    int b = blockIdx.z;
    int m0 = blockIdx.y * 128;
    int n0 = blockIdx.x * 128;
    int t = threadIdx.x, w = t >> 6, l = t & 63;
    int wr = w >> 1, wc = w & 1;
    int lr = l >> 4, lc = l & 15;
    f32x4 acc[4][4];
    const f32x4 fz = {0.f, 0.f, 0.f, 0.f};
#pragma unroll
    for (int i = 0; i < 4; i++)
#pragma unroll
        for (int j = 0; j < 4; j++) acc[i][j] = fz;
    const F16* cb = ctxT + (size_t)b * NN * KCH;

    for (int kt = 0; kt < KCH / 32; kt++) {
        int c0 = kt * 32;
        __syncthreads();
#pragma unroll
        for (int p = 0; p < 4; p++) {
            int row = (t >> 3) + p * 32;
            int cc = (t & 7) * 4;
            float4 v = *(const float4*)&w_w[(size_t)(m0 + row) * KCH + c0 + cc];
            f16x4 h; h[0] = (F16)v.x; h[1] = (F16)v.y; h[2] = (F16)v.z; h[3] = (F16)v.w;
            *(f16x4*)&Al[row][cc] = h;
        }
#pragma unroll
        for (int p = 0; p < 2; p++) {
            int row = (t >> 2) + p * 64;
            int cc = (t & 3) * 8;
            *(int4*)&Bl[row][cc] = *(const int4*)&cb[(size_t)(n0 + row) * KCH + c0 + cc];
        }
        __syncthreads();
        f16x8 a[4];
#pragma unroll
        for (int fi = 0; fi < 4; fi++)
            a[fi] = *(f16x8*)&Al[wr * 64 + fi * 16 + lc][lr * 8];
#pragma unroll
        for (int fj = 0; fj < 4; fj++) {
            f16x8 bb = *(f16x8*)&Bl[wc * 64 + fj * 16 + lc][lr * 8];
#pragma unroll
            for (int fi = 0; fi < 4; fi++)
                acc[fi][fj] = __builtin_amdgcn_mfma_f32_16x16x32_f16(a[fi], bb, acc[fi][fj], 0, 0, 0);
        }
    }

#pragma unroll
    for (int fi = 0; fi < 4; fi++) {
        int o0 = m0 + wr * 64 + fi * 16 + lr * 4;
#pragma unroll
        for (int fj = 0; fj < 4; fj++) {
            int n = n0 + wc * 64 + fj * 16 + lc;
#pragma unroll
            for (int r = 0; r < 4; r++) {
                out[((size_t)b * OCH + o0 + r) * NN + n] = acc[fi][fj][r] + w_b[o0 + r];
            }
        }
    }
}

// ---------------------------------------------------------------- launch
extern "C" void kernel_launch(void* const* d_in, const int* in_sizes, int n_in,
                              void* d_out, int out_size, void* d_ws, size_t ws_size,
                              hipStream_t stream) {
    const float* x       = (const float*)d_in[0];
    const float* key_w   = (const float*)d_in[1];
    const float* key_b   = (const float*)d_in[2];
    const float* gamma   = (const float*)d_in[3];
    const float* beta    = (const float*)d_in[4];
    const float* mean    = (const float*)d_in[5];
    const float* var     = (const float*)d_in[6];
    const float* value_w = (const float*)d_in[7];
    const float* value_b = (const float*)d_in[8];
    const float* w_w     = (const float*)d_in[9];
    const float* w_b     = (const float*)d_in[10];
    float* out = (float*)d_out;
    char* ws = (char*)d_ws;

    // layout (ws_size >= 50.6 MB proven by round-4 run taking the 4-set path):
    // parts 4*8.39M | KQt 8.39M (ctxT overlays) | Vg 8.39M | L 256K
    size_t kqt_off = 4 * PSET * 2;
    size_t vg_off  = kqt_off + 8388608ull;
    size_t l_off   = vg_off + 8388608ull;

    F16*   xT    = (F16*)(ws);                 // dead after kv_gemm; parts overlay
    F16*   parts = (F16*)(ws);
    F16*   KQt   = (F16*)(ws + kqt_off);
    F16*   ctxT  = (F16*)(ws + kqt_off);       // overlays KQt (dead after flash)
    F16*   Vg    = (F16*)(ws + vg_off);
    float* Lbuf  = (float*)(ws + l_off);

    hipLaunchKernelGGL(k_transpose, dim3(8, 64, 4), dim3(256), 0, stream, x, xT);
    hipLaunchKernelGGL(k_kv_gemm, dim3(32, 4, 4), dim3(256), 0, stream,
                       xT, key_w, key_b, gamma, beta, mean, var, value_w, value_b, KQt, Vg);
    hipLaunchKernelGGL(k_flash, dim3(512), dim3(256), 0, stream, KQt, Vg, parts, Lbuf);
    hipLaunchKernelGGL(k_combine, dim3(2048), dim3(256), 0, stream, parts, Lbuf, ctxT);
    hipLaunchKernelGGL(k_out_gemm, dim3(32, 4, 4), dim3(256), 0, stream, ctxT, w_w, w_b, out);
}

// Round 6
// 204.885 us; speedup vs baseline: 1.5530x; 1.4315x over previous
//
#include <hip/hip_runtime.h>

#define F16 _Float16
typedef _Float16 f16x8 __attribute__((ext_vector_type(8)));
typedef _Float16 f16x4 __attribute__((ext_vector_type(4)));
typedef float f32x4 __attribute__((ext_vector_type(4)));

#define NB    4
#define CIN   512
#define NN    4096
#define KCH   256
#define OCH   512
#define BNEPS 1e-5f
#define PSET  ((size_t)NB * NN * KCH)        // elements per partial set
#define NBNN  (NB * NN)

// ---------------------------------------------------------------- transpose
__global__ __launch_bounds__(256) void k_transpose(const float* __restrict__ x,
                                                   F16* __restrict__ xT) {
    __shared__ float tile[64][65];
    int b = blockIdx.z, n0 = blockIdx.y * 64, c0 = blockIdx.x * 64;
    int t = threadIdx.x;
    const float* xb = x + (size_t)b * CIN * NN;
#pragma unroll
    for (int i = 0; i < 4; i++) {
        int c = (t >> 4) + i * 16;
        int n = (t & 15) * 4;
        float4 v = *(const float4*)&xb[(size_t)(c0 + c) * NN + n0 + n];
        tile[c][n + 0] = v.x; tile[c][n + 1] = v.y;
        tile[c][n + 2] = v.z; tile[c][n + 3] = v.w;
    }
    __syncthreads();
    F16* xTb = xT + (size_t)b * NN * CIN;
#pragma unroll
    for (int i = 0; i < 4; i++) {
        int n = (t >> 4) + i * 16;
        int c = (t & 15) * 4;
        f16x4 o;
        o[0] = (F16)tile[c + 0][n]; o[1] = (F16)tile[c + 1][n];
        o[2] = (F16)tile[c + 2][n]; o[3] = (F16)tile[c + 3][n];
        *(f16x4*)&xTb[(size_t)(n0 + n) * CIN + c0 + c] = o;
    }
}

// ---------------------------------------------------------------- K/V GEMM
__global__ __launch_bounds__(256) void k_kv_gemm(
    const F16* __restrict__ xT,
    const float* __restrict__ key_w, const float* __restrict__ key_b,
    const float* __restrict__ gamma, const float* __restrict__ beta,
    const float* __restrict__ mean,  const float* __restrict__ var,
    const float* __restrict__ value_w, const float* __restrict__ value_b,
    F16* __restrict__ KQt, F16* __restrict__ Vg) {
    __shared__ F16 Al[128][40];
    __shared__ F16 Bl[128][40];
    int b = blockIdx.z;
    int m0 = blockIdx.y * 128;
    int n0 = blockIdx.x * 128;
    int t = threadIdx.x, w = t >> 6, l = t & 63;
    int wr = w >> 1, wc = w & 1;
    int lr = l >> 4, lc = l & 15;
    f32x4 acc[4][4];
    const f32x4 fz = {0.f, 0.f, 0.f, 0.f};
#pragma unroll
    for (int i = 0; i < 4; i++)
#pragma unroll
        for (int j = 0; j < 4; j++) acc[i][j] = fz;
    const F16* xb = xT + (size_t)b * NN * CIN;

    for (int kt = 0; kt < CIN / 32; kt++) {
        int c0 = kt * 32;
        __syncthreads();
#pragma unroll
        for (int p = 0; p < 4; p++) {
            int row = (t >> 3) + p * 32;
            int cc = (t & 7) * 4;
            int rg = m0 + row;
            const float* src = (rg < 256) ? (key_w + (size_t)rg * CIN)
                                          : (value_w + (size_t)(rg - 256) * CIN);
            float4 v = *(const float4*)&src[c0 + cc];
            f16x4 h; h[0] = (F16)v.x; h[1] = (F16)v.y; h[2] = (F16)v.z; h[3] = (F16)v.w;
            *(f16x4*)&Al[row][cc] = h;
        }
#pragma unroll
        for (int p = 0; p < 2; p++) {
            int row = (t >> 2) + p * 64;
            int cc = (t & 3) * 8;
            *(int4*)&Bl[row][cc] = *(const int4*)&xb[(size_t)(n0 + row) * CIN + c0 + cc];
        }
        __syncthreads();
        f16x8 a[4];
#pragma unroll
        for (int fi = 0; fi < 4; fi++)
            a[fi] = *(f16x8*)&Al[wr * 64 + fi * 16 + lc][lr * 8];
#pragma unroll
        for (int fj = 0; fj < 4; fj++) {
            f16x8 bb = *(f16x8*)&Bl[wc * 64 + fj * 16 + lc][lr * 8];
#pragma unroll
            for (int fi = 0; fi < 4; fi++)
                acc[fi][fj] = __builtin_amdgcn_mfma_f32_16x16x32_f16(a[fi], bb, acc[fi][fj], 0, 0, 0);
        }
    }

    if (m0 < 256) {
#pragma unroll
        for (int fi = 0; fi < 4; fi++) {
            int ch0 = m0 + wr * 64 + fi * 16 + lr * 4;
            float invs[4], mns[4], bts[4], kbs[4];
#pragma unroll
            for (int r = 0; r < 4; r++) {
                int ch = ch0 + r;
                invs[r] = gamma[ch] * rsqrtf(var[ch] + BNEPS);
                mns[r] = mean[ch]; bts[r] = beta[ch]; kbs[r] = key_b[ch];
            }
#pragma unroll
            for (int fj = 0; fj < 4; fj++) {
                int n = n0 + wc * 64 + fj * 16 + lc;
                f16x4 o;
#pragma unroll
                for (int r = 0; r < 4; r++) {
                    float v = (acc[fi][fj][r] + kbs[r] - mns[r]) * invs[r] + bts[r];
                    v = fmaxf(v, 0.0f);
                    o[r] = (F16)v;
                }
                *(f16x4*)&KQt[((size_t)b * NN + n) * KCH + ch0] = o;
            }
        }
    } else {
#pragma unroll
        for (int fi = 0; fi < 4; fi++) {
            int v0 = m0 - 256 + wr * 64 + fi * 16 + lr * 4;
#pragma unroll
            for (int fj = 0; fj < 4; fj++) {
                int n = n0 + wc * 64 + fj * 16 + lc;
#pragma unroll
                for (int r = 0; r < 4; r++) {
                    float vv = acc[fi][fj][r] + value_b[v0 + r];
                    Vg[((size_t)b * KCH + v0 + r) * NN + n] = (F16)vv;
                }
            }
        }
    }
}

// ---------------------------------------------------------------- flash attention
// Round-3 skeleton (16 q-rows/wave, split-K S=2, 512 blocks = 2/CU) with
// PV split across waves by v-channel: P is block-shared; wave w computes
// ctx v-slice [w*64, w*64+64) over all 64 q-rows. Softmax rescale factors
// broadcast via corr[64] LDS (branchless always-multiply).
__global__ __launch_bounds__(256, 2) void k_flash(const F16* __restrict__ KQt,
                                                  const F16* __restrict__ Vg,
                                                  F16* __restrict__ parts,
                                                  float* __restrict__ Lbuf) {
    __shared__ __align__(16) F16 Kl[64 * 264];
    __shared__ __align__(16) F16 Vl[256 * 72];
    __shared__ __align__(16) F16 Ps[64 * 72];
    __shared__ __align__(16) float crl[64];     // corr per step; l_tot at epilogue
    int bid = blockIdx.x;
    int xcd = bid & 7;
    int b = xcd >> 1;                          // batch pinned to an XCD pair
    int hi = bid >> 3;                         // 0..63
    int kset = hi & 1;                         // 2 key-streams per XCD (R3 regime)
    int qtile = (xcd & 1) * 32 + (hi >> 1);    // 0..63
    int n0 = qtile * 64;
    int kbase = kset * 2048;
    int t = threadIdx.x, w = t >> 6, l = t & 63;
    int lr = l >> 4, lc = l & 15;
    int vs = w * 64;                           // this wave's v-slice for PV
    const F16* kqb = KQt + (size_t)b * NN * KCH;
    const F16* vgb = Vg + (size_t)b * KCH * NN;
    const float scale = 0.0625f;

    // Q tile -> registers (A-fragment: row = w*16+lc, cols = ks*32 + lr*8)
    f16x8 qreg[8];
    {
        const F16* qrow = kqb + (size_t)(n0 + w * 16 + lc) * KCH + lr * 8;
#pragma unroll
        for (int ks = 0; ks < 8; ks++)
            qreg[ks] = *(const f16x8*)&qrow[ks * 32];
    }

    f32x4 acc[4][4];                           // [qf][fv]: 64 q-rows x 64 v-slice
    const f32x4 fz = {0.f, 0.f, 0.f, 0.f};
#pragma unroll
    for (int i = 0; i < 4; i++)
#pragma unroll
        for (int j = 0; j < 4; j++) acc[i][j] = fz;
    float m_run[4] = {-1e30f, -1e30f, -1e30f, -1e30f};
    float l_run[4] = {0.f, 0.f, 0.f, 0.f};

    int krow = t >> 5, kcol = (t & 31) * 8;    // K staging: 8 rows/pass
    int vrow = t >> 3, vcol = (t & 7) * 8;     // V staging: 32 rows/pass

    for (int mt = 0; mt < 32; mt++) {
        int m0 = kbase + mt * 64;
        __syncthreads();                       // prev PV done with Kl/Vl/Ps
#pragma unroll
        for (int p = 0; p < 8; p++) {
            int4 tmp = *(const int4*)&kqb[(size_t)(m0 + krow + p * 8) * KCH + kcol];
            *(int4*)&Kl[(krow + p * 8) * 264 + kcol] = tmp;
        }
#pragma unroll
        for (int p = 0; p < 8; p++) {
            int4 tmp = *(const int4*)&vgb[(size_t)(vrow + p * 32) * NN + m0 + vcol];
            *(int4*)&Vl[(vrow + p * 32) * 72 + vcol] = tmp;
        }
        __syncthreads();                       // tiles visible

        // S = Q K^T  (wave: 16 q-rows x 64 k-cols, contraction 256)
        f32x4 s[4];
#pragma unroll
        for (int f = 0; f < 4; f++) s[f] = fz;
#pragma unroll
        for (int ks = 0; ks < 8; ks++) {
#pragma unroll
            for (int f = 0; f < 4; f++) {
                f16x8 bb = *(f16x8*)&Kl[(f * 16 + lc) * 264 + ks * 32 + lr * 8];
                s[f] = __builtin_amdgcn_mfma_f32_16x16x32_f16(qreg[ks], bb, s[f], 0, 0, 0);
            }
        }

        // online softmax (deferred rescale THR=8); q-row = w*16 + lr*4 + r
#pragma unroll
        for (int r = 0; r < 4; r++) {
            float mx = fmaxf(fmaxf(s[0][r], s[1][r]), fmaxf(s[2][r], s[3][r]));
#pragma unroll
            for (int off = 1; off < 16; off <<= 1)
                mx = fmaxf(mx, __shfl_xor(mx, off, 64));
            mx *= scale;
            float corr = 1.0f;
            if (mx > m_run[r] + 8.0f) {
                corr = __expf(m_run[r] - mx);
                m_run[r] = mx;
                l_run[r] *= corr;
            }
            float ps = 0.0f;
#pragma unroll
            for (int f = 0; f < 4; f++) {
                float p = __expf(s[f][r] * scale - m_run[r]);
                ps += p;
                Ps[(w * 16 + lr * 4 + r) * 72 + f * 16 + lc] = (F16)p;
            }
#pragma unroll
            for (int off = 1; off < 16; off <<= 1)
                ps += __shfl_xor(ps, off, 64);
            l_run[r] += ps;
            if (lc == 0) crl[w * 16 + lr * 4 + r] = corr;
        }
        __syncthreads();                       // P + corr visible to all waves

        // rescale full acc (all 64 q-rows) by broadcast corr — branchless
#pragma unroll
        for (int qf = 0; qf < 4; qf++) {
            f32x4 c4 = *(f32x4*)&crl[qf * 16 + lr * 4];
#pragma unroll
            for (int fv = 0; fv < 4; fv++)
#pragma unroll
                for (int rr = 0; rr < 4; rr++)
                    acc[qf][fv][rr] *= c4[rr];
        }

        // PV: wave's v-slice [vs, vs+64) over all 64 q-rows; B reused across qf
#pragma unroll
        for (int ks = 0; ks < 2; ks++) {
            f16x8 pa[4];
#pragma unroll
            for (int qf = 0; qf < 4; qf++)
                pa[qf] = *(f16x8*)&Ps[(qf * 16 + lc) * 72 + ks * 32 + lr * 8];
#pragma unroll
            for (int fv = 0; fv < 4; fv++) {
                f16x8 bb = *(f16x8*)&Vl[(vs + fv * 16 + lc) * 72 + ks * 32 + lr * 8];
#pragma unroll
                for (int qf = 0; qf < 4; qf++)
                    acc[qf][fv] = __builtin_amdgcn_mfma_f32_16x16x32_f16(pa[qf], bb, acc[qf][fv], 0, 0, 0);
            }
        }
    }

    // epilogue: share l_tot, then write normalized partial + L
    __syncthreads();
    if (lc == 0) {
#pragma unroll
        for (int r = 0; r < 4; r++)
            crl[w * 16 + lr * 4 + r] = l_run[r];
    }
    __syncthreads();

    F16* cb = parts + (size_t)kset * PSET + (size_t)b * NN * KCH;
#pragma unroll
    for (int qf = 0; qf < 4; qf++) {
        f32x4 l4 = *(f32x4*)&crl[qf * 16 + lr * 4];
#pragma unroll
        for (int r = 0; r < 4; r++) {
            int n = n0 + qf * 16 + lr * 4 + r;
            float inv = 1.0f / l4[r];
#pragma unroll
            for (int fv = 0; fv < 4; fv++)
                cb[(size_t)n * KCH + vs + fv * 16 + lc] = (F16)(acc[qf][fv][r] * inv);
        }
    }
    float* Lb = Lbuf + ((size_t)kset * NB + b) * NN;
    if (lc == 0) {
#pragma unroll
        for (int r = 0; r < 4; r++)
            Lb[n0 + w * 16 + lr * 4 + r] = m_run[r] + __logf(l_run[r]);
    }
}

// ---------------------------------------------------------------- combine (2-way split-K merge)
__global__ __launch_bounds__(256) void k_combine(const F16* __restrict__ parts,
                                                 const float* __restrict__ Lbuf,
                                                 F16* __restrict__ ctxT) {
    int idx = blockIdx.x * 256 + threadIdx.x;       // over B*N*32
    int n = idx >> 5;
    int v8 = (idx & 31) * 8;
    float L0 = Lbuf[n], L1 = Lbuf[NBNN + n];
    float M = fmaxf(L0, L1);
    float w0 = __expf(L0 - M), w1 = __expf(L1 - M);
    float inv = 1.0f / (w0 + w1);
    w0 *= inv; w1 *= inv;
    f16x8 p0 = *(const f16x8*)&parts[(size_t)n * KCH + v8];
    f16x8 p1 = *(const f16x8*)&parts[PSET + (size_t)n * KCH + v8];
    f16x8 o;
#pragma unroll
    for (int j = 0; j < 8; j++)
        o[j] = (F16)(w0 * (float)p0[j] + w1 * (float)p1[j]);
    *(f16x8*)&ctxT[(size_t)n * KCH + v8] = o;
}

// ---------------------------------------------------------------- out GEMM
__global__ __launch_bounds__(256) void k_out_gemm(const F16* __restrict__ ctxT,
                                                  const float* __restrict__ w_w,
                                                  const float* __restrict__ w_b,
                                                  float* __restrict__ out) {
    __shared__ F16 Al[128][40];
    __shared__ F16 Bl[128][40];
    int b = blockIdx.z;
    int m0 = blockIdx.y * 128;
    int n0 = blockIdx.x * 128;
    int t = threadIdx.x, w = t >> 6, l = t & 63;
    int wr = w >> 1, wc = w & 1;
    int lr = l >> 4, lc = l & 15;
    f32x4 acc[4][4];
    const f32x4 fz = {0.f, 0.f, 0.f, 0.f};
#pragma unroll
    for (int i = 0; i < 4; i++)
#pragma unroll
        for (int j = 0; j < 4; j++) acc[i][j] = fz;
    const F16* cb = ctxT + (size_t)b * NN * KCH;

    for (int kt = 0; kt < KCH / 32; kt++) {
        int c0 = kt * 32;
        __syncthreads();
#pragma unroll
        for (int p = 0; p < 4; p++) {
            int row = (t >> 3) + p * 32;
            int cc = (t & 7) * 4;
            float4 v = *(const float4*)&w_w[(size_t)(m0 + row) * KCH + c0 + cc];
            f16x4 h; h[0] = (F16)v.x; h[1] = (F16)v.y; h[2] = (F16)v.z; h[3] = (F16)v.w;
            *(f16x4*)&Al[row][cc] = h;
        }
#pragma unroll
        for (int p = 0; p < 2; p++) {
            int row = (t >> 2) + p * 64;
            int cc = (t & 3) * 8;
            *(int4*)&Bl[row][cc] = *(const int4*)&cb[(size_t)(n0 + row) * KCH + c0 + cc];
        }
        __syncthreads();
        f16x8 a[4];
#pragma unroll
        for (int fi = 0; fi < 4; fi++)
            a[fi] = *(f16x8*)&Al[wr * 64 + fi * 16 + lc][lr * 8];
#pragma unroll
        for (int fj = 0; fj < 4; fj++) {
            f16x8 bb = *(f16x8*)&Bl[wc * 64 + fj * 16 + lc][lr * 8];
#pragma unroll
            for (int fi = 0; fi < 4; fi++)
                acc[fi][fj] = __builtin_amdgcn_mfma_f32_16x16x32_f16(a[fi], bb, acc[fi][fj], 0, 0, 0);
        }
    }

#pragma unroll
    for (int fi = 0; fi < 4; fi++) {
        int o0 = m0 + wr * 64 + fi * 16 + lr * 4;
#pragma unroll
        for (int fj = 0; fj < 4; fj++) {
            int n = n0 + wc * 64 + fj * 16 + lc;
#pragma unroll
            for (int r = 0; r < 4; r++) {
                out[((size_t)b * OCH + o0 + r) * NN + n] = acc[fi][fj][r] + w_b[o0 + r];
            }
        }
    }
}

// ---------------------------------------------------------------- launch
extern "C" void kernel_launch(void* const* d_in, const int* in_sizes, int n_in,
                              void* d_out, int out_size, void* d_ws, size_t ws_size,
                              hipStream_t stream) {
    const float* x       = (const float*)d_in[0];
    const float* key_w   = (const float*)d_in[1];
    const float* key_b   = (const float*)d_in[2];
    const float* gamma   = (const float*)d_in[3];
    const float* beta    = (const float*)d_in[4];
    const float* mean    = (const float*)d_in[5];
    const float* var     = (const float*)d_in[6];
    const float* value_w = (const float*)d_in[7];
    const float* value_b = (const float*)d_in[8];
    const float* w_w     = (const float*)d_in[9];
    const float* w_b     = (const float*)d_in[10];
    float* out = (float*)d_out;
    char* ws = (char*)d_ws;

    // layout (round-3 proven): parts 2*8.39M (overlays dead xT) | KQt 8.39M
    // (ctxT overlays after flash) | Vg 8.39M | L 128K
    size_t kqt_off = 2 * PSET * 2;
    size_t vg_off  = kqt_off + 8388608ull;
    size_t l_off   = vg_off + 8388608ull;

    F16*   xT    = (F16*)(ws);
    F16*   parts = (F16*)(ws);
    F16*   KQt   = (F16*)(ws + kqt_off);
    F16*   ctxT  = (F16*)(ws + kqt_off);
    F16*   Vg    = (F16*)(ws + vg_off);
    float* Lbuf  = (float*)(ws + l_off);

    hipLaunchKernelGGL(k_transpose, dim3(8, 64, 4), dim3(256), 0, stream, x, xT);
    hipLaunchKernelGGL(k_kv_gemm, dim3(32, 4, 4), dim3(256), 0, stream,
                       xT, key_w, key_b, gamma, beta, mean, var, value_w, value_b, KQt, Vg);
    hipLaunchKernelGGL(k_flash, dim3(512), dim3(256), 0, stream, KQt, Vg, parts, Lbuf);
    hipLaunchKernelGGL(k_combine, dim3(2048), dim3(256), 0, stream, parts, Lbuf, ctxT);
    hipLaunchKernelGGL(k_out_gemm, dim3(32, 4, 4), dim3(256), 0, stream, ctxT, w_w, w_b, out);
}

// Round 7
// 158.235 us; speedup vs baseline: 2.0109x; 1.2948x over previous
//
#include <hip/hip_runtime.h>

#define F16 _Float16
typedef _Float16 f16x8 __attribute__((ext_vector_type(8)));
typedef _Float16 f16x4 __attribute__((ext_vector_type(4)));
typedef float f32x4 __attribute__((ext_vector_type(4)));

#define NB    4
#define CIN   512
#define NN    4096
#define KCH   256
#define OCH   512
#define BNEPS 1e-5f
#define PSET  ((size_t)NB * NN * KCH)        // elements per partial set
#define NBNN  (NB * NN)

// async global->LDS, 16B per lane (dest = uniform base + lane*16)
__device__ __forceinline__ void gl16(const F16* g, F16* l) {
    __builtin_amdgcn_global_load_lds((const __attribute__((address_space(1))) void*)g,
                                     (__attribute__((address_space(3))) void*)l, 16, 0, 0);
}

// ---------------------------------------------------------------- transpose
__global__ __launch_bounds__(256) void k_transpose(const float* __restrict__ x,
                                                   F16* __restrict__ xT) {
    __shared__ float tile[64][65];
    int b = blockIdx.z, n0 = blockIdx.y * 64, c0 = blockIdx.x * 64;
    int t = threadIdx.x;
    const float* xb = x + (size_t)b * CIN * NN;
#pragma unroll
    for (int i = 0; i < 4; i++) {
        int c = (t >> 4) + i * 16;
        int n = (t & 15) * 4;
        float4 v = *(const float4*)&xb[(size_t)(c0 + c) * NN + n0 + n];
        tile[c][n + 0] = v.x; tile[c][n + 1] = v.y;
        tile[c][n + 2] = v.z; tile[c][n + 3] = v.w;
    }
    __syncthreads();
    F16* xTb = xT + (size_t)b * NN * CIN;
#pragma unroll
    for (int i = 0; i < 4; i++) {
        int n = (t >> 4) + i * 16;
        int c = (t & 15) * 4;
        f16x4 o;
        o[0] = (F16)tile[c + 0][n]; o[1] = (F16)tile[c + 1][n];
        o[2] = (F16)tile[c + 2][n]; o[3] = (F16)tile[c + 3][n];
        *(f16x4*)&xTb[(size_t)(n0 + n) * CIN + c0 + c] = o;
    }
}

// ---------------------------------------------------------------- K/V GEMM
__global__ __launch_bounds__(256) void k_kv_gemm(
    const F16* __restrict__ xT,
    const float* __restrict__ key_w, const float* __restrict__ key_b,
    const float* __restrict__ gamma, const float* __restrict__ beta,
    const float* __restrict__ mean,  const float* __restrict__ var,
    const float* __restrict__ value_w, const float* __restrict__ value_b,
    F16* __restrict__ KQt, F16* __restrict__ Vg) {
    __shared__ F16 Al[128][40];
    __shared__ F16 Bl[128][40];
    int b = blockIdx.z;
    int m0 = blockIdx.y * 128;
    int n0 = blockIdx.x * 128;
    int t = threadIdx.x, w = t >> 6, l = t & 63;
    int wr = w >> 1, wc = w & 1;
    int lr = l >> 4, lc = l & 15;
    f32x4 acc[4][4];
    const f32x4 fz = {0.f, 0.f, 0.f, 0.f};
#pragma unroll
    for (int i = 0; i < 4; i++)
#pragma unroll
        for (int j = 0; j < 4; j++) acc[i][j] = fz;
    const F16* xb = xT + (size_t)b * NN * CIN;

    for (int kt = 0; kt < CIN / 32; kt++) {
        int c0 = kt * 32;
        __syncthreads();
#pragma unroll
        for (int p = 0; p < 4; p++) {
            int row = (t >> 3) + p * 32;
            int cc = (t & 7) * 4;
            int rg = m0 + row;
            const float* src = (rg < 256) ? (key_w + (size_t)rg * CIN)
                                          : (value_w + (size_t)(rg - 256) * CIN);
            float4 v = *(const float4*)&src[c0 + cc];
            f16x4 h; h[0] = (F16)v.x; h[1] = (F16)v.y; h[2] = (F16)v.z; h[3] = (F16)v.w;
            *(f16x4*)&Al[row][cc] = h;
        }
#pragma unroll
        for (int p = 0; p < 2; p++) {
            int row = (t >> 2) + p * 64;
            int cc = (t & 3) * 8;
            *(int4*)&Bl[row][cc] = *(const int4*)&xb[(size_t)(n0 + row) * CIN + c0 + cc];
        }
        __syncthreads();
        f16x8 a[4];
#pragma unroll
        for (int fi = 0; fi < 4; fi++)
            a[fi] = *(f16x8*)&Al[wr * 64 + fi * 16 + lc][lr * 8];
#pragma unroll
        for (int fj = 0; fj < 4; fj++) {
            f16x8 bb = *(f16x8*)&Bl[wc * 64 + fj * 16 + lc][lr * 8];
#pragma unroll
            for (int fi = 0; fi < 4; fi++)
                acc[fi][fj] = __builtin_amdgcn_mfma_f32_16x16x32_f16(a[fi], bb, acc[fi][fj], 0, 0, 0);
        }
    }

    if (m0 < 256) {
#pragma unroll
        for (int fi = 0; fi < 4; fi++) {
            int ch0 = m0 + wr * 64 + fi * 16 + lr * 4;
            float invs[4], mns[4], bts[4], kbs[4];
#pragma unroll
            for (int r = 0; r < 4; r++) {
                int ch = ch0 + r;
                invs[r] = gamma[ch] * rsqrtf(var[ch] + BNEPS);
                mns[r] = mean[ch]; bts[r] = beta[ch]; kbs[r] = key_b[ch];
            }
#pragma unroll
            for (int fj = 0; fj < 4; fj++) {
                int n = n0 + wc * 64 + fj * 16 + lc;
                f16x4 o;
#pragma unroll
                for (int r = 0; r < 4; r++) {
                    float v = (acc[fi][fj][r] + kbs[r] - mns[r]) * invs[r] + bts[r];
                    v = fmaxf(v, 0.0f);
                    o[r] = (F16)v;
                }
                *(f16x4*)&KQt[((size_t)b * NN + n) * KCH + ch0] = o;
            }
        }
    } else {
#pragma unroll
        for (int fi = 0; fi < 4; fi++) {
            int v0 = m0 - 256 + wr * 64 + fi * 16 + lr * 4;
#pragma unroll
            for (int fj = 0; fj < 4; fj++) {
                int n = n0 + wc * 64 + fj * 16 + lc;
#pragma unroll
                for (int r = 0; r < 4; r++) {
                    float vv = acc[fi][fj][r] + value_b[v0 + r];
                    Vg[((size_t)b * KCH + v0 + r) * NN + n] = (F16)vv;
                }
            }
        }
    }
}

// ---------------------------------------------------------------- flash attention
// R6 skeleton (16 q-rows/wave, PV split by v-slice, split-K S=2, 512 blocks =
// 2/CU) with: global_load_lds staging (pre-swizzled global source, linear LDS
// dest), XOR-swizzled K/V/P reads (chunk ^= row&7, 16B chunks), defer-max with
// __all fast path, and l-sum accumulated via MFMA against an all-ones fragment.
// LDS: K 32KB + V 32KB + P 8KB + crl = 74.2KB.
__global__ __launch_bounds__(256, 2) void k_flash(const F16* __restrict__ KQt,
                                                  const F16* __restrict__ Vg,
                                                  F16* __restrict__ parts,
                                                  float* __restrict__ Lbuf) {
    __shared__ __align__(16) F16 Kl[64 * 256];    // row stride 512B (32 chunks)
    __shared__ __align__(16) F16 Vl[256 * 64];    // row stride 128B (8 chunks)
    __shared__ __align__(16) F16 Ps[64 * 64];     // row stride 128B (8 chunks)
    __shared__ __align__(16) float crl[64];
    int bid = blockIdx.x;
    int xcd = bid & 7;
    int b = xcd >> 1;                          // batch pinned to an XCD pair
    int hi = bid >> 3;                         // 0..63
    int kset = hi & 1;                         // 2 key-streams per XCD
    int qtile = (xcd & 1) * 32 + (hi >> 1);    // 0..63
    int n0 = qtile * 64;
    int kbase = kset * 2048;
    int t = threadIdx.x, w = t >> 6, l = t & 63;
    int lr = l >> 4, lc = l & 15;
    int kx = lc & 7;                           // read-side XOR (row&7 for rows ≡ lc mod 8)
    int vs = w * 64;                           // wave's v-slice for PV
    const F16* kqb = KQt + (size_t)b * NN * KCH;
    const F16* vgb = Vg + (size_t)b * KCH * NN;
    const float scale = 0.0625f;

    // Q tile -> registers (A-fragment: row = w*16+lc, k-cols = ks*32 + lr*8)
    f16x8 qreg[8];
    {
        const F16* qrow = kqb + (size_t)(n0 + w * 16 + lc) * KCH + lr * 8;
#pragma unroll
        for (int ks = 0; ks < 8; ks++)
            qreg[ks] = *(const f16x8*)&qrow[ks * 32];
    }
    f16x8 one8;
#pragma unroll
    for (int j = 0; j < 8; j++) one8[j] = (F16)1.0f;

    f32x4 acc[4][4];                           // [qf][fv]: 64 q-rows x 64 v-slice
    const f32x4 fz = {0.f, 0.f, 0.f, 0.f};
#pragma unroll
    for (int i = 0; i < 4; i++)
#pragma unroll
        for (int j = 0; j < 4; j++) acc[i][j] = fz;
    f32x4 lsum = fz;                           // per own q-row softmax denominator
    float m_run[4] = {-1e30f, -1e30f, -1e30f, -1e30f};

    // staging lane constants
    int khalf = l >> 5;                        // 0..1 (row within pair)
    int kc = l & 31;                           // K chunk slot
    int vloc = l >> 3;                         // 0..7 (row within octet)
    int vc = l & 7;                            // V chunk slot

    for (int mt = 0; mt < 32; mt++) {
        int m0 = kbase + mt * 64;
        __syncthreads();                       // all waves done reading Kl/Vl/Ps
        // async stage K rows [w*16, w*16+16): 8 calls x (2 rows x 32 chunks)
#pragma unroll
        for (int p = 0; p < 8; p++) {
            int row = w * 16 + 2 * p + khalf;              // row in tile
            int srcc = kc ^ (row & 7);                     // pre-swizzled source
            gl16(kqb + (size_t)(m0 + row) * KCH + srcc * 8,
                 &Kl[(w * 16 + 2 * p) * 256]);
        }
        // async stage V rows [w*64, w*64+64): 8 calls x (8 rows x 8 chunks)
#pragma unroll
        for (int p = 0; p < 8; p++) {
            int row = w * 64 + 8 * p + vloc;               // v-channel
            int srcc = vc ^ (row & 7);
            gl16(vgb + (size_t)row * NN + m0 + srcc * 8,
                 &Vl[(w * 64 + 8 * p) * 64]);
        }
        __syncthreads();                       // vmcnt(0) drain -> tile visible

        // S = Q K^T (wave: 16 q-rows x 64 k-cols, contraction 256)
        f32x4 s[4];
#pragma unroll
        for (int f = 0; f < 4; f++) s[f] = fz;
#pragma unroll
        for (int ks = 0; ks < 8; ks++) {
#pragma unroll
            for (int f = 0; f < 4; f++) {
                f16x8 bb = *(f16x8*)&Kl[(f * 16 + lc) * 256 + (((ks * 4 + lr) ^ kx) << 3)];
                s[f] = __builtin_amdgcn_mfma_f32_16x16x32_f16(qreg[ks], bb, s[f], 0, 0, 0);
            }
        }

        // defer-max online softmax: lane-local guard, rare wave-reduce path
        float lm[4], cr[4];
#pragma unroll
        for (int r = 0; r < 4; r++) {
            lm[r] = fmaxf(fmaxf(s[0][r], s[1][r]), fmaxf(s[2][r], s[3][r])) * scale;
            cr[r] = 1.0f;
        }
        int ok = (lm[0] <= m_run[0] + 8.0f) && (lm[1] <= m_run[1] + 8.0f) &&
                 (lm[2] <= m_run[2] + 8.0f) && (lm[3] <= m_run[3] + 8.0f);
        if (!__all(ok)) {
#pragma unroll
            for (int r = 0; r < 4; r++) {
                float mx = lm[r];
#pragma unroll
                for (int off = 1; off < 16; off <<= 1)
                    mx = fmaxf(mx, __shfl_xor(mx, off, 64));
                float mnew = fmaxf(m_run[r], mx);
                cr[r] = __expf(m_run[r] - mnew);
                m_run[r] = mnew;
                lsum[r] *= cr[r];
            }
        }
        if (lc == 0) {
#pragma unroll
            for (int r = 0; r < 4; r++) crl[w * 16 + lr * 4 + r] = cr[r];
        }
        // P = exp(s*scale - m_run) -> swizzled Ps
#pragma unroll
        for (int r = 0; r < 4; r++) {
            int prow = w * 16 + lr * 4 + r;
            int px = prow & 7;
#pragma unroll
            for (int f = 0; f < 4; f++) {
                float p = __expf(s[f][r] * scale - m_run[r]);
                Ps[prow * 64 + ((((f * 2) + (lc >> 3)) ^ px) << 3) + (lc & 7)] = (F16)p;
            }
        }
        __syncthreads();                       // P + corr visible to all waves

        // rescale acc (all 64 q-rows) by broadcast corr
#pragma unroll
        for (int qf = 0; qf < 4; qf++) {
            f32x4 c4 = *(f32x4*)&crl[qf * 16 + lr * 4];
#pragma unroll
            for (int fv = 0; fv < 4; fv++)
#pragma unroll
                for (int rr = 0; rr < 4; rr++)
                    acc[qf][fv][rr] *= c4[rr];
        }

        // PV (wave's v-slice over all 64 q-rows) + l-sum MFMA (own rows x ones)
#pragma unroll
        for (int ks = 0; ks < 2; ks++) {
            f16x8 pown = *(f16x8*)&Ps[(w * 16 + lc) * 64 + (((ks * 4 + lr) ^ kx) << 3)];
            lsum = __builtin_amdgcn_mfma_f32_16x16x32_f16(pown, one8, lsum, 0, 0, 0);
            f16x8 pa[4];
#pragma unroll
            for (int qf = 0; qf < 4; qf++)
                pa[qf] = *(f16x8*)&Ps[(qf * 16 + lc) * 64 + (((ks * 4 + lr) ^ kx) << 3)];
#pragma unroll
            for (int fv = 0; fv < 4; fv++) {
                f16x8 bb = *(f16x8*)&Vl[(vs + fv * 16 + lc) * 64 + (((ks * 4 + lr) ^ kx) << 3)];
#pragma unroll
                for (int qf = 0; qf < 4; qf++)
                    acc[qf][fv] = __builtin_amdgcn_mfma_f32_16x16x32_f16(pa[qf], bb, acc[qf][fv], 0, 0, 0);
            }
        }
    }

    // epilogue: share l, then write normalized partial + L
    __syncthreads();
    if (lc == 0) {
#pragma unroll
        for (int r = 0; r < 4; r++) crl[w * 16 + lr * 4 + r] = lsum[r];
    }
    __syncthreads();

    F16* cb = parts + (size_t)kset * PSET + (size_t)b * NN * KCH;
#pragma unroll
    for (int qf = 0; qf < 4; qf++) {
        f32x4 l4 = *(f32x4*)&crl[qf * 16 + lr * 4];
#pragma unroll
        for (int r = 0; r < 4; r++) {
            int n = n0 + qf * 16 + lr * 4 + r;
            float inv = 1.0f / l4[r];
#pragma unroll
            for (int fv = 0; fv < 4; fv++)
                cb[(size_t)n * KCH + vs + fv * 16 + lc] = (F16)(acc[qf][fv][r] * inv);
        }
    }
    float* Lb = Lbuf + ((size_t)kset * NB + b) * NN;
    if (lc == 0) {
#pragma unroll
        for (int r = 0; r < 4; r++)
            Lb[n0 + w * 16 + lr * 4 + r] = m_run[r] + __logf(lsum[r]);
    }
}

// ---------------------------------------------------------------- combine (2-way split-K merge)
__global__ __launch_bounds__(256) void k_combine(const F16* __restrict__ parts,
                                                 const float* __restrict__ Lbuf,
                                                 F16* __restrict__ ctxT) {
    int idx = blockIdx.x * 256 + threadIdx.x;       // over B*N*32
    int n = idx >> 5;
    int v8 = (idx & 31) * 8;
    float L0 = Lbuf[n], L1 = Lbuf[NBNN + n];
    float M = fmaxf(L0, L1);
    float w0 = __expf(L0 - M), w1 = __expf(L1 - M);
    float inv = 1.0f / (w0 + w1);
    w0 *= inv; w1 *= inv;
    f16x8 p0 = *(const f16x8*)&parts[(size_t)n * KCH + v8];
    f16x8 p1 = *(const f16x8*)&parts[PSET + (size_t)n * KCH + v8];
    f16x8 o;
#pragma unroll
    for (int j = 0; j < 8; j++)
        o[j] = (F16)(w0 * (float)p0[j] + w1 * (float)p1[j]);
    *(f16x8*)&ctxT[(size_t)n * KCH + v8] = o;
}

// ---------------------------------------------------------------- out GEMM
__global__ __launch_bounds__(256) void k_out_gemm(const F16* __restrict__ ctxT,
                                                  const float* __restrict__ w_w,
                                                  const float* __restrict__ w_b,
                                                  float* __restrict__ out) {
    __shared__ F16 Al[128][40];
    __shared__ F16 Bl[128][40];
    int b = blockIdx.z;
    int m0 = blockIdx.y * 128;
    int n0 = blockIdx.x * 128;
    int t = threadIdx.x, w = t >> 6, l = t & 63;
    int wr = w >> 1, wc = w & 1;
    int lr = l >> 4, lc = l & 15;
    f32x4 acc[4][4];
    const f32x4 fz = {0.f, 0.f, 0.f, 0.f};
#pragma unroll
    for (int i = 0; i < 4; i++)
#pragma unroll
        for (int j = 0; j < 4; j++) acc[i][j] = fz;
    const F16* cb = ctxT + (size_t)b * NN * KCH;

    for (int kt = 0; kt < KCH / 32; kt++) {
        int c0 = kt * 32;
        __syncthreads();
#pragma unroll
        for (int p = 0; p < 4; p++) {
            int row = (t >> 3) + p * 32;
            int cc = (t & 7) * 4;
            float4 v = *(const float4*)&w_w[(size_t)(m0 + row) * KCH + c0 + cc];
            f16x4 h; h[0] = (F16)v.x; h[1] = (F16)v.y; h[2] = (F16)v.z; h[3] = (F16)v.w;
            *(f16x4*)&Al[row][cc] = h;
        }
#pragma unroll
        for (int p = 0; p < 2; p++) {
            int row = (t >> 2) + p * 64;
            int cc = (t & 3) * 8;
            *(int4*)&Bl[row][cc] = *(const int4*)&cb[(size_t)(n0 + row) * KCH + c0 + cc];
        }
        __syncthreads();
        f16x8 a[4];
#pragma unroll
        for (int fi = 0; fi < 4; fi++)
            a[fi] = *(f16x8*)&Al[wr * 64 + fi * 16 + lc][lr * 8];
#pragma unroll
        for (int fj = 0; fj < 4; fj++) {
            f16x8 bb = *(f16x8*)&Bl[wc * 64 + fj * 16 + lc][lr * 8];
#pragma unroll
            for (int fi = 0; fi < 4; fi++)
                acc[fi][fj] = __builtin_amdgcn_mfma_f32_16x16x32_f16(a[fi], bb, acc[fi][fj], 0, 0, 0);
        }
    }

#pragma unroll
    for (int fi = 0; fi < 4; fi++) {
        int o0 = m0 + wr * 64 + fi * 16 + lr * 4;
#pragma unroll
        for (int fj = 0; fj < 4; fj++) {
            int n = n0 + wc * 64 + fj * 16 + lc;
#pragma unroll
            for (int r = 0; r < 4; r++) {
                out[((size_t)b * OCH + o0 + r) * NN + n] = acc[fi][fj][r] + w_b[o0 + r];
            }
        }
    }
}

// ---------------------------------------------------------------- launch
extern "C" void kernel_launch(void* const* d_in, const int* in_sizes, int n_in,
                              void* d_out, int out_size, void* d_ws, size_t ws_size,
                              hipStream_t stream) {
    const float* x       = (const float*)d_in[0];
    const float* key_w   = (const float*)d_in[1];
    const float* key_b   = (const float*)d_in[2];
    const float* gamma   = (const float*)d_in[3];
    const float* beta    = (const float*)d_in[4];
    const float* mean    = (const float*)d_in[5];
    const float* var     = (const float*)d_in[6];
    const float* value_w = (const float*)d_in[7];
    const float* value_b = (const float*)d_in[8];
    const float* w_w     = (const float*)d_in[9];
    const float* w_b     = (const float*)d_in[10];
    float* out = (float*)d_out;
    char* ws = (char*)d_ws;

    // layout: parts 2*8.39M (overlays dead xT) | KQt 8.39M (ctxT overlays
    // after flash) | Vg 8.39M | L 128K
    size_t kqt_off = 2 * PSET * 2;
    size_t vg_off  = kqt_off + 8388608ull;
    size_t l_off   = vg_off + 8388608ull;

    F16*   xT    = (F16*)(ws);
    F16*   parts = (F16*)(ws);
    F16*   KQt   = (F16*)(ws + kqt_off);
    F16*   ctxT  = (F16*)(ws + kqt_off);
    F16*   Vg    = (F16*)(ws + vg_off);
    float* Lbuf  = (float*)(ws + l_off);

    hipLaunchKernelGGL(k_transpose, dim3(8, 64, 4), dim3(256), 0, stream, x, xT);
    hipLaunchKernelGGL(k_kv_gemm, dim3(32, 4, 4), dim3(256), 0, stream,
                       xT, key_w, key_b, gamma, beta, mean, var, value_w, value_b, KQt, Vg);
    hipLaunchKernelGGL(k_flash, dim3(512), dim3(256), 0, stream, KQt, Vg, parts, Lbuf);
    hipLaunchKernelGGL(k_combine, dim3(2048), dim3(256), 0, stream, parts, Lbuf, ctxT);
    hipLaunchKernelGGL(k_out_gemm, dim3(32, 4, 4), dim3(256), 0, stream, ctxT, w_w, w_b, out);
}

// Round 8
// 141.468 us; speedup vs baseline: 2.2492x; 1.1185x over previous
//
#include <hip/hip_runtime.h>

#define F16 _Float16
typedef _Float16 f16x8 __attribute__((ext_vector_type(8)));
typedef _Float16 f16x4 __attribute__((ext_vector_type(4)));
typedef float f32x4 __attribute__((ext_vector_type(4)));

#define NB    4
#define CIN   512
#define NN    4096
#define KCH   256
#define OCH   512
#define BNEPS 1e-5f
#define PSET  ((size_t)NB * NN * KCH)        // elements per partial set
#define NBNN  (NB * NN)

// async global->LDS, 16B per lane (dest = uniform base + lane*16)
__device__ __forceinline__ void gl16(const F16* g, F16* l) {
    __builtin_amdgcn_global_load_lds((const __attribute__((address_space(1))) void*)g,
                                     (__attribute__((address_space(3))) void*)l, 16, 0, 0);
}

// ---------------------------------------------------------------- transpose
__global__ __launch_bounds__(256) void k_transpose(const float* __restrict__ x,
                                                   F16* __restrict__ xT) {
    __shared__ float tile[64][65];
    int b = blockIdx.z, n0 = blockIdx.y * 64, c0 = blockIdx.x * 64;
    int t = threadIdx.x;
    const float* xb = x + (size_t)b * CIN * NN;
#pragma unroll
    for (int i = 0; i < 4; i++) {
        int c = (t >> 4) + i * 16;
        int n = (t & 15) * 4;
        float4 v = *(const float4*)&xb[(size_t)(c0 + c) * NN + n0 + n];
        tile[c][n + 0] = v.x; tile[c][n + 1] = v.y;
        tile[c][n + 2] = v.z; tile[c][n + 3] = v.w;
    }
    __syncthreads();
    F16* xTb = xT + (size_t)b * NN * CIN;
#pragma unroll
    for (int i = 0; i < 4; i++) {
        int n = (t >> 4) + i * 16;
        int c = (t & 15) * 4;
        f16x4 o;
        o[0] = (F16)tile[c + 0][n]; o[1] = (F16)tile[c + 1][n];
        o[2] = (F16)tile[c + 2][n]; o[3] = (F16)tile[c + 3][n];
        *(f16x4*)&xTb[(size_t)(n0 + n) * CIN + c0 + c] = o;
    }
}

// ---------------------------------------------------------------- K/V GEMM
__global__ __launch_bounds__(256) void k_kv_gemm(
    const F16* __restrict__ xT,
    const float* __restrict__ key_w, const float* __restrict__ key_b,
    const float* __restrict__ gamma, const float* __restrict__ beta,
    const float* __restrict__ mean,  const float* __restrict__ var,
    const float* __restrict__ value_w, const float* __restrict__ value_b,
    F16* __restrict__ KQt, F16* __restrict__ Vg) {
    __shared__ F16 Al[128][40];
    __shared__ F16 Bl[128][40];
    int b = blockIdx.z;
    int m0 = blockIdx.y * 128;
    int n0 = blockIdx.x * 128;
    int t = threadIdx.x, w = t >> 6, l = t & 63;
    int wr = w >> 1, wc = w & 1;
    int lr = l >> 4, lc = l & 15;
    f32x4 acc[4][4];
    const f32x4 fz = {0.f, 0.f, 0.f, 0.f};
#pragma unroll
    for (int i = 0; i < 4; i++)
#pragma unroll
        for (int j = 0; j < 4; j++) acc[i][j] = fz;
    const F16* xb = xT + (size_t)b * NN * CIN;

    for (int kt = 0; kt < CIN / 32; kt++) {
        int c0 = kt * 32;
        __syncthreads();
#pragma unroll
        for (int p = 0; p < 4; p++) {
            int row = (t >> 3) + p * 32;
            int cc = (t & 7) * 4;
            int rg = m0 + row;
            const float* src = (rg < 256) ? (key_w + (size_t)rg * CIN)
                                          : (value_w + (size_t)(rg - 256) * CIN);
            float4 v = *(const float4*)&src[c0 + cc];
            f16x4 h; h[0] = (F16)v.x; h[1] = (F16)v.y; h[2] = (F16)v.z; h[3] = (F16)v.w;
            *(f16x4*)&Al[row][cc] = h;
        }
#pragma unroll
        for (int p = 0; p < 2; p++) {
            int row = (t >> 2) + p * 64;
            int cc = (t & 3) * 8;
            *(int4*)&Bl[row][cc] = *(const int4*)&xb[(size_t)(n0 + row) * CIN + c0 + cc];
        }
        __syncthreads();
        f16x8 a[4];
#pragma unroll
        for (int fi = 0; fi < 4; fi++)
            a[fi] = *(f16x8*)&Al[wr * 64 + fi * 16 + lc][lr * 8];
#pragma unroll
        for (int fj = 0; fj < 4; fj++) {
            f16x8 bb = *(f16x8*)&Bl[wc * 64 + fj * 16 + lc][lr * 8];
#pragma unroll
            for (int fi = 0; fi < 4; fi++)
                acc[fi][fj] = __builtin_amdgcn_mfma_f32_16x16x32_f16(a[fi], bb, acc[fi][fj], 0, 0, 0);
        }
    }

    if (m0 < 256) {
#pragma unroll
        for (int fi = 0; fi < 4; fi++) {
            int ch0 = m0 + wr * 64 + fi * 16 + lr * 4;
            float invs[4], mns[4], bts[4], kbs[4];
#pragma unroll
            for (int r = 0; r < 4; r++) {
                int ch = ch0 + r;
                invs[r] = gamma[ch] * rsqrtf(var[ch] + BNEPS);
                mns[r] = mean[ch]; bts[r] = beta[ch]; kbs[r] = key_b[ch];
            }
#pragma unroll
            for (int fj = 0; fj < 4; fj++) {
                int n = n0 + wc * 64 + fj * 16 + lc;
                f16x4 o;
#pragma unroll
                for (int r = 0; r < 4; r++) {
                    float v = (acc[fi][fj][r] + kbs[r] - mns[r]) * invs[r] + bts[r];
                    v = fmaxf(v, 0.0f);
                    o[r] = (F16)v;
                }
                *(f16x4*)&KQt[((size_t)b * NN + n) * KCH + ch0] = o;
            }
        }
    } else {
#pragma unroll
        for (int fi = 0; fi < 4; fi++) {
            int v0 = m0 - 256 + wr * 64 + fi * 16 + lr * 4;
#pragma unroll
            for (int fj = 0; fj < 4; fj++) {
                int n = n0 + wc * 64 + fj * 16 + lc;
#pragma unroll
                for (int r = 0; r < 4; r++) {
                    float vv = acc[fi][fj][r] + value_b[v0 + r];
                    Vg[((size_t)b * KCH + v0 + r) * NN + n] = (F16)vv;
                }
            }
        }
    }
}

// ---------------------------------------------------------------- flash attention
// R7 structure + (a) P-swizzle px=(row>>1)&7 -> conflict-free scalar P writes,
// (b) block-wide rescale-skip flag (double-buffered) -> acc rescale only on
// the rare steps where some row's max actually grew.
__global__ __launch_bounds__(256, 2) void k_flash(const F16* __restrict__ KQt,
                                                  const F16* __restrict__ Vg,
                                                  F16* __restrict__ parts,
                                                  float* __restrict__ Lbuf) {
    __shared__ __align__(16) F16 Kl[64 * 256];    // row stride 512B (32 chunks)
    __shared__ __align__(16) F16 Vl[256 * 64];    // row stride 128B (8 chunks)
    __shared__ __align__(16) F16 Ps[64 * 64];     // row stride 128B (8 chunks)
    __shared__ __align__(16) float crl[64];
    __shared__ int rflag[2];
    int bid = blockIdx.x;
    int xcd = bid & 7;
    int b = xcd >> 1;                          // batch pinned to an XCD pair
    int hi = bid >> 3;                         // 0..63
    int kset = hi & 1;                         // 2 key-streams per XCD
    int qtile = (xcd & 1) * 32 + (hi >> 1);    // 0..63
    int n0 = qtile * 64;
    int kbase = kset * 2048;
    int t = threadIdx.x, w = t >> 6, l = t & 63;
    int lr = l >> 4, lc = l & 15;
    int kx = lc & 7;                           // K/V read XOR (row&7 congruent)
    int pxr = (lc >> 1) & 7;                   // P read XOR ((row>>1)&7 congruent)
    int vs = w * 64;                           // wave's v-slice for PV
    const F16* kqb = KQt + (size_t)b * NN * KCH;
    const F16* vgb = Vg + (size_t)b * KCH * NN;
    const float scale = 0.0625f;

    if (t == 0) { rflag[0] = 0; rflag[1] = 0; }

    // Q tile -> registers (A-fragment: row = w*16+lc, k-cols = ks*32 + lr*8)
    f16x8 qreg[8];
    {
        const F16* qrow = kqb + (size_t)(n0 + w * 16 + lc) * KCH + lr * 8;
#pragma unroll
        for (int ks = 0; ks < 8; ks++)
            qreg[ks] = *(const f16x8*)&qrow[ks * 32];
    }
    f16x8 one8;
#pragma unroll
    for (int j = 0; j < 8; j++) one8[j] = (F16)1.0f;

    f32x4 acc[4][4];                           // [qf][fv]: 64 q-rows x 64 v-slice
    const f32x4 fz = {0.f, 0.f, 0.f, 0.f};
#pragma unroll
    for (int i = 0; i < 4; i++)
#pragma unroll
        for (int j = 0; j < 4; j++) acc[i][j] = fz;
    f32x4 lsum = fz;                           // own q-rows softmax denominator
    float m_run[4] = {-1e30f, -1e30f, -1e30f, -1e30f};

    // staging lane constants
    int khalf = l >> 5;                        // 0..1 (row within pair)
    int kc = l & 31;                           // K chunk slot
    int vloc = l >> 3;                         // 0..7 (row within octet)
    int vc = l & 7;                            // V chunk slot

    for (int mt = 0; mt < 32; mt++) {
        int m0 = kbase + mt * 64;
        __syncthreads();                       // all waves done reading Kl/Vl/Ps
#pragma unroll
        for (int p = 0; p < 8; p++) {
            int row = w * 16 + 2 * p + khalf;
            int srcc = kc ^ (row & 7);
            gl16(kqb + (size_t)(m0 + row) * KCH + srcc * 8,
                 &Kl[(w * 16 + 2 * p) * 256]);
        }
#pragma unroll
        for (int p = 0; p < 8; p++) {
            int row = w * 64 + 8 * p + vloc;
            int srcc = vc ^ (row & 7);
            gl16(vgb + (size_t)row * NN + m0 + srcc * 8,
                 &Vl[(w * 64 + 8 * p) * 64]);
        }
        __syncthreads();                       // drain -> tiles visible

        // S = Q K^T (wave: 16 q-rows x 64 k-cols, contraction 256)
        f32x4 s[4];
#pragma unroll
        for (int f = 0; f < 4; f++) s[f] = fz;
#pragma unroll
        for (int ks = 0; ks < 8; ks++) {
#pragma unroll
            for (int f = 0; f < 4; f++) {
                f16x8 bb = *(f16x8*)&Kl[(f * 16 + lc) * 256 + (((ks * 4 + lr) ^ kx) << 3)];
                s[f] = __builtin_amdgcn_mfma_f32_16x16x32_f16(qreg[ks], bb, s[f], 0, 0, 0);
            }
        }

        // defer-max online softmax: lane-local guard, rare wave-reduce path
        float lm[4], cr[4];
#pragma unroll
        for (int r = 0; r < 4; r++) {
            lm[r] = fmaxf(fmaxf(s[0][r], s[1][r]), fmaxf(s[2][r], s[3][r])) * scale;
            cr[r] = 1.0f;
        }
        int ok = (lm[0] <= m_run[0] + 8.0f) && (lm[1] <= m_run[1] + 8.0f) &&
                 (lm[2] <= m_run[2] + 8.0f) && (lm[3] <= m_run[3] + 8.0f);
        if (!__all(ok)) {
#pragma unroll
            for (int r = 0; r < 4; r++) {
                float mx = lm[r];
#pragma unroll
                for (int off = 1; off < 16; off <<= 1)
                    mx = fmaxf(mx, __shfl_xor(mx, off, 64));
                float mnew = fmaxf(m_run[r], mx);
                cr[r] = __expf(m_run[r] - mnew);
                m_run[r] = mnew;
                lsum[r] *= cr[r];
            }
            if (l == 0) rflag[mt & 1] = 1;     // block must rescale this step
        }
        if (lc == 0) {
#pragma unroll
            for (int r = 0; r < 4; r++) crl[w * 16 + lr * 4 + r] = cr[r];
        }
        // P = exp(s*scale - m_run) -> swizzled Ps (px = (row>>1)&7)
#pragma unroll
        for (int r = 0; r < 4; r++) {
            int prow = w * 16 + lr * 4 + r;
            int px = (prow >> 1) & 7;
#pragma unroll
            for (int f = 0; f < 4; f++) {
                float p = __expf(s[f][r] * scale - m_run[r]);
                Ps[prow * 64 + ((((f * 2) + (lc >> 3)) ^ px) << 3) + (lc & 7)] = (F16)p;
            }
        }
        if (t == 0) rflag[(mt + 1) & 1] = 0;   // pre-clear next step's flag
        __syncthreads();                       // P + corr + flag visible

        // rescale acc only when some row actually rescaled this step
        if (rflag[mt & 1]) {
#pragma unroll
            for (int qf = 0; qf < 4; qf++) {
                f32x4 c4 = *(f32x4*)&crl[qf * 16 + lr * 4];
#pragma unroll
                for (int fv = 0; fv < 4; fv++)
#pragma unroll
                    for (int rr = 0; rr < 4; rr++)
                        acc[qf][fv][rr] *= c4[rr];
            }
        }

        // PV (wave's v-slice over all 64 q-rows) + l-sum MFMA (own rows x ones)
#pragma unroll
        for (int ks = 0; ks < 2; ks++) {
            f16x8 pown = *(f16x8*)&Ps[(w * 16 + lc) * 64 + (((ks * 4 + lr) ^ pxr) << 3)];
            lsum = __builtin_amdgcn_mfma_f32_16x16x32_f16(pown, one8, lsum, 0, 0, 0);
            f16x8 pa[4];
#pragma unroll
            for (int qf = 0; qf < 4; qf++)
                pa[qf] = *(f16x8*)&Ps[(qf * 16 + lc) * 64 + (((ks * 4 + lr) ^ pxr) << 3)];
#pragma unroll
            for (int fv = 0; fv < 4; fv++) {
                f16x8 bb = *(f16x8*)&Vl[(vs + fv * 16 + lc) * 64 + (((ks * 4 + lr) ^ kx) << 3)];
#pragma unroll
                for (int qf = 0; qf < 4; qf++)
                    acc[qf][fv] = __builtin_amdgcn_mfma_f32_16x16x32_f16(pa[qf], bb, acc[qf][fv], 0, 0, 0);
            }
        }
    }

    // epilogue: share l, then write normalized partial + L
    __syncthreads();
    if (lc == 0) {
#pragma unroll
        for (int r = 0; r < 4; r++) crl[w * 16 + lr * 4 + r] = lsum[r];
    }
    __syncthreads();

    F16* cb = parts + (size_t)kset * PSET + (size_t)b * NN * KCH;
#pragma unroll
    for (int qf = 0; qf < 4; qf++) {
        f32x4 l4 = *(f32x4*)&crl[qf * 16 + lr * 4];
#pragma unroll
        for (int r = 0; r < 4; r++) {
            int n = n0 + qf * 16 + lr * 4 + r;
            float inv = 1.0f / l4[r];
#pragma unroll
            for (int fv = 0; fv < 4; fv++)
                cb[(size_t)n * KCH + vs + fv * 16 + lc] = (F16)(acc[qf][fv][r] * inv);
        }
    }
    float* Lb = Lbuf + ((size_t)kset * NB + b) * NN;
    if (lc == 0) {
#pragma unroll
        for (int r = 0; r < 4; r++)
            Lb[n0 + w * 16 + lr * 4 + r] = m_run[r] + __logf(lsum[r]);
    }
}

// ---------------------------------------------------------------- out GEMM (fused split-K merge)
// B-staging merges the two normalized partials with softmax-LSE weights.
__global__ __launch_bounds__(256) void k_out_gemm(const F16* __restrict__ parts,
                                                  const float* __restrict__ Lbuf,
                                                  const float* __restrict__ w_w,
                                                  const float* __restrict__ w_b,
                                                  float* __restrict__ out) {
    __shared__ F16 Al[128][40];
    __shared__ F16 Bl[128][40];
    __shared__ float lw0[128], lw1[128];
    int b = blockIdx.z;
    int m0 = blockIdx.y * 128;
    int n0 = blockIdx.x * 128;
    int t = threadIdx.x, w = t >> 6, l = t & 63;
    int wr = w >> 1, wc = w & 1;
    int lr = l >> 4, lc = l & 15;

    if (t < 128) {
        int n = n0 + t;
        float L0 = Lbuf[(size_t)b * NN + n];
        float L1 = Lbuf[(size_t)NBNN + (size_t)b * NN + n];
        float M = fmaxf(L0, L1);
        float e0 = __expf(L0 - M), e1 = __expf(L1 - M);
        float inv = 1.0f / (e0 + e1);
        lw0[t] = e0 * inv; lw1[t] = e1 * inv;
    }
    __syncthreads();
    int row0 = t >> 2, row1 = (t >> 2) + 64;
    float w00 = lw0[row0], w10 = lw1[row0];
    float w01 = lw0[row1], w11 = lw1[row1];

    f32x4 acc[4][4];
    const f32x4 fz = {0.f, 0.f, 0.f, 0.f};
#pragma unroll
    for (int i = 0; i < 4; i++)
#pragma unroll
        for (int j = 0; j < 4; j++) acc[i][j] = fz;

    for (int kt = 0; kt < KCH / 32; kt++) {
        int c0 = kt * 32;
        __syncthreads();
#pragma unroll
        for (int p = 0; p < 4; p++) {
            int row = (t >> 3) + p * 32;
            int cc = (t & 7) * 4;
            float4 v = *(const float4*)&w_w[(size_t)(m0 + row) * KCH + c0 + cc];
            f16x4 h; h[0] = (F16)v.x; h[1] = (F16)v.y; h[2] = (F16)v.z; h[3] = (F16)v.w;
            *(f16x4*)&Al[row][cc] = h;
        }
#pragma unroll
        for (int p = 0; p < 2; p++) {
            int row = (p == 0) ? row0 : row1;
            float wa = (p == 0) ? w00 : w01;
            float wb2 = (p == 0) ? w10 : w11;
            int cc = (t & 3) * 8;
            size_t base = ((size_t)b * NN + n0 + row) * KCH + c0 + cc;
            f16x8 p0 = *(const f16x8*)&parts[base];
            f16x8 p1 = *(const f16x8*)&parts[PSET + base];
            f16x8 m;
#pragma unroll
            for (int j = 0; j < 8; j++)
                m[j] = (F16)(wa * (float)p0[j] + wb2 * (float)p1[j]);
            *(f16x8*)&Bl[row][cc] = m;
        }
        __syncthreads();
        f16x8 a[4];
#pragma unroll
        for (int fi = 0; fi < 4; fi++)
            a[fi] = *(f16x8*)&Al[wr * 64 + fi * 16 + lc][lr * 8];
#pragma unroll
        for (int fj = 0; fj < 4; fj++) {
            f16x8 bb = *(f16x8*)&Bl[wc * 64 + fj * 16 + lc][lr * 8];
#pragma unroll
            for (int fi = 0; fi < 4; fi++)
                acc[fi][fj] = __builtin_amdgcn_mfma_f32_16x16x32_f16(a[fi], bb, acc[fi][fj], 0, 0, 0);
        }
    }

#pragma unroll
    for (int fi = 0; fi < 4; fi++) {
        int o0 = m0 + wr * 64 + fi * 16 + lr * 4;
#pragma unroll
        for (int fj = 0; fj < 4; fj++) {
            int n = n0 + wc * 64 + fj * 16 + lc;
#pragma unroll
            for (int r = 0; r < 4; r++) {
                out[((size_t)b * OCH + o0 + r) * NN + n] = acc[fi][fj][r] + w_b[o0 + r];
            }
        }
    }
}

// ---------------------------------------------------------------- launch
extern "C" void kernel_launch(void* const* d_in, const int* in_sizes, int n_in,
                              void* d_out, int out_size, void* d_ws, size_t ws_size,
                              hipStream_t stream) {
    const float* x       = (const float*)d_in[0];
    const float* key_w   = (const float*)d_in[1];
    const float* key_b   = (const float*)d_in[2];
    const float* gamma   = (const float*)d_in[3];
    const float* beta    = (const float*)d_in[4];
    const float* mean    = (const float*)d_in[5];
    const float* var     = (const float*)d_in[6];
    const float* value_w = (const float*)d_in[7];
    const float* value_b = (const float*)d_in[8];
    const float* w_w     = (const float*)d_in[9];
    const float* w_b     = (const float*)d_in[10];
    float* out = (float*)d_out;
    char* ws = (char*)d_ws;

    // layout: parts 2*8.39M (overlays dead xT) | KQt 8.39M | Vg 8.39M | L 128K
    size_t kqt_off = 2 * PSET * 2;
    size_t vg_off  = kqt_off + 8388608ull;
    size_t l_off   = vg_off + 8388608ull;

    F16*   xT    = (F16*)(ws);
    F16*   parts = (F16*)(ws);
    F16*   KQt   = (F16*)(ws + kqt_off);
    F16*   Vg    = (F16*)(ws + vg_off);
    float* Lbuf  = (float*)(ws + l_off);

    hipLaunchKernelGGL(k_transpose, dim3(8, 64, 4), dim3(256), 0, stream, x, xT);
    hipLaunchKernelGGL(k_kv_gemm, dim3(32, 4, 4), dim3(256), 0, stream,
                       xT, key_w, key_b, gamma, beta, mean, var, value_w, value_b, KQt, Vg);
    hipLaunchKernelGGL(k_flash, dim3(512), dim3(256), 0, stream, KQt, Vg, parts, Lbuf);
    hipLaunchKernelGGL(k_out_gemm, dim3(32, 4, 4), dim3(256), 0, stream,
                       parts, Lbuf, w_w, w_b, out);
}